// Round 11
// baseline (327.020 us; speedup 1.0000x reference)
//
#include <hip/hip_runtime.h>

#define NB 64
#define NT 512
#define NVAR 16
#define VDIM 16
#define DD 64
#define FF 256
#define BT (NB*NT)
#define LN_EPS 1e-3f
#define LOG2E 1.4426950408889634f

typedef __attribute__((ext_vector_type(8))) short bf8;   // 8 bf16 = one MFMA A/B operand
typedef __attribute__((ext_vector_type(4))) float f4;
typedef __attribute__((ext_vector_type(4))) int i4;
typedef __attribute__((ext_vector_type(4))) unsigned u4;

// ---- ws layout (bytes) ----
// ALGEBRAIC FOLDS (all exact fp32 at prep):
//   rpb[n]     = bt@Wp + bp                      (res bias, per var)
//   cpb1[b][n] = (ctx@Wctx + bt)@W1 + b1         (h1 bias, per batch-var)
//   wtpf       = Wt@Wp, wt1f = Wt@W1             (K=16 mats off xv)
//   wgcf       = log2e*W2@Wg, bgc = log2e*(b2@Wg+bg)  (gate through W2)
// vsn walls per var-pair: A) fused K=16 quad off xv_a,xv_b  B_a, B_b) K=64 pairs off h1.
#define CPB1_OFF   0                  // 64*16*64 f32 = 256KB
#define RPB_OFF    262144             // 16*64 f32 = 4KB
#define WTPP_OFF   266240             // packed Wt@Wp: 16v x 4Mi x 64 x 16B = 64KB
#define WT1P_OFF   331776             // packed Wt@W1: 64KB
#define BIGP_OFF   397312             // 2 mats x 16v x 16 frags x 64 x 16B = 512KB
#define WSP_OFF    921600             // 16 frags x 64 x 16B = 16KB
#define BGC_OFF    937984             // 16*64 f32 = 4KB
#define WGCF_OFF   942080             // wgc float intermediate 256KB
#define WTPF_OFF   1204224            // Wt@Wp float intermediate 64KB
#define WT1F_OFF   1269760            // Wt@W1 float intermediate 64KB
// bigp frag layout per var-mat (16 frags): idx = (c*2+hl)*4 + Mi ; mats 0=W2 1=wgcf

// ---- precise RNE split (prep-time only) ----
__device__ __forceinline__ void split1(float x, unsigned &hb, float &lo) {
    unsigned u = __builtin_bit_cast(unsigned, x);
    unsigned r = u + 0x7fffu + ((u >> 16) & 1u);
    hb = r >> 16;
    lo = x - __builtin_bit_cast(float, r & 0xffff0000u);
}
__device__ __forceinline__ unsigned rnepk(float x, float y) {
    unsigned a = __builtin_bit_cast(unsigned, x);
    unsigned b = __builtin_bit_cast(unsigned, y);
    a = a + 0x7fffu + ((a >> 16) & 1u);
    b = b + 0x7fffu + ((b >> 16) & 1u);
    return (a >> 16) | (b & 0xffff0000u);
}
__device__ __forceinline__ void split4(f4 v, unsigned &h0, unsigned &h1,
                                       unsigned &l0, unsigned &l1) {
    unsigned b0,b1,b2,b3; float q0,q1,q2,q3;
    split1(v.x,b0,q0); split1(v.y,b1,q1); split1(v.z,b2,q2); split1(v.w,b3,q3);
    h0 = b0 | (b1<<16); h1 = b2 | (b3<<16);
    l0 = rnepk(q0,q1); l1 = rnepk(q2,q3);
}
// ---- fast truncation split (hot path): hi = trunc(x), lo = trunc(x - hi) ----
__device__ __forceinline__ void split4f(f4 v, unsigned &h0, unsigned &h1,
                                        unsigned &l0, unsigned &l1) {
    unsigned a0 = __builtin_bit_cast(unsigned, v.x);
    unsigned a1 = __builtin_bit_cast(unsigned, v.y);
    unsigned a2 = __builtin_bit_cast(unsigned, v.z);
    unsigned a3 = __builtin_bit_cast(unsigned, v.w);
    unsigned m0 = a0 & 0xffff0000u, m1 = a1 & 0xffff0000u;
    unsigned m2 = a2 & 0xffff0000u, m3 = a3 & 0xffff0000u;
    h0 = (a0 >> 16) | m1;
    h1 = (a2 >> 16) | m3;
    float lx = v.x - __builtin_bit_cast(float, m0);
    float ly = v.y - __builtin_bit_cast(float, m1);
    float lz = v.z - __builtin_bit_cast(float, m2);
    float lw = v.w - __builtin_bit_cast(float, m3);
    l0 = (__builtin_bit_cast(unsigned, lx) >> 16) |
         (__builtin_bit_cast(unsigned, ly) & 0xffff0000u);
    l1 = (__builtin_bit_cast(unsigned, lz) >> 16) |
         (__builtin_bit_cast(unsigned, lw) & 0xffff0000u);
}
__device__ __forceinline__ bf8 afrag(u4 w) { return __builtin_bit_cast(bf8, w); }
__device__ __forceinline__ bf8 mk_b4(unsigned w0, unsigned w1, unsigned w2, unsigned w3) {
    i4 t; t.x = (int)w0; t.y = (int)w1; t.z = (int)w2; t.w = (int)w3;
    return __builtin_bit_cast(bf8, t);
}
// duplicated-B operands (K=16 stages)
__device__ __forceinline__ bf8 mk_bhh(unsigned h0, unsigned h1) {
    i4 t; t.x = (int)h0; t.y = (int)h1; t.z = (int)h0; t.w = (int)h1;
    return __builtin_bit_cast(bf8, t);
}
__device__ __forceinline__ bf8 mk_bl0(unsigned l0, unsigned l1) {
    i4 t; t.x = (int)l0; t.y = (int)l1; t.z = 0; t.w = 0;
    return __builtin_bit_cast(bf8, t);
}

__device__ __forceinline__ f4 mfma2(f4 acc, bf8 Af, bf8 Bh, bf8 Bl) {
    acc = __builtin_amdgcn_mfma_f32_16x16x32_bf16(Af, Bh, acc, 0,0,0);
    acc = __builtin_amdgcn_mfma_f32_16x16x32_bf16(Af, Bl, acc, 0,0,0);
    return acc;
}

// acc (C-layout) -> B-operand frags of the next stage (pure in-lane repack)
__device__ __forceinline__ void acc_to_frags1(const f4 acc[4],
        unsigned fh[4][2], unsigned fl[4][2]) {
    #pragma unroll
    for (int Ks = 0; Ks < 4; ++Ks)
        split4f(acc[Ks], fh[Ks][0], fh[Ks][1], fl[Ks][0], fl[Ks][1]);
}
__device__ __forceinline__ void elu4(f4* v) {
    #pragma unroll
    for (int Mi = 0; Mi < 4; ++Mi) {
        f4& x = v[Mi];
        x.x = x.x > 0.f ? x.x : (__expf(x.x)-1.f);
        x.y = x.y > 0.f ? x.y : (__expf(x.y)-1.f);
        x.z = x.z > 0.f ? x.z : (__expf(x.z)-1.f);
        x.w = x.w > 0.f ? x.w : (__expf(x.w)-1.f);
    }
}
// Paired 64x64 GEMM-stage, full-K: both mats consume the SAME B operands.
// 6 MFMAs per Mi per mat; terms Wh.xh + Wl.xh + Wh.xl (Wl.xl ~2^-16 dropped).
__device__ __forceinline__ void run_stage6_pair(const u4* __restrict__ ap0,
        const u4* __restrict__ ap1, int lane,
        const unsigned fh[4][2], const unsigned fl[4][2], f4 acc0[4], f4 acc1[4]) {
    const bf8 Bh0 = mk_b4(fh[0][0], fh[0][1], fh[1][0], fh[1][1]);
    const bf8 Bh1 = mk_b4(fh[2][0], fh[2][1], fh[3][0], fh[3][1]);
    const bf8 Bl0 = mk_b4(fl[0][0], fl[0][1], fl[1][0], fl[1][1]);
    const bf8 Bl1 = mk_b4(fl[2][0], fl[2][1], fl[3][0], fl[3][1]);
    #pragma unroll
    for (int Mi = 0; Mi < 4; ++Mi) {
        {
            const u4 ah0 = ap0[(     Mi)*64 + lane];
            const u4 al0 = ap0[( 4 + Mi)*64 + lane];
            const u4 ah1 = ap0[( 8 + Mi)*64 + lane];
            const u4 al1 = ap0[(12 + Mi)*64 + lane];
            f4 a = acc0[Mi];
            a = __builtin_amdgcn_mfma_f32_16x16x32_bf16(afrag(ah0), Bh0, a, 0,0,0);
            a = __builtin_amdgcn_mfma_f32_16x16x32_bf16(afrag(ah1), Bh1, a, 0,0,0);
            a = __builtin_amdgcn_mfma_f32_16x16x32_bf16(afrag(al0), Bh0, a, 0,0,0);
            a = __builtin_amdgcn_mfma_f32_16x16x32_bf16(afrag(al1), Bh1, a, 0,0,0);
            a = __builtin_amdgcn_mfma_f32_16x16x32_bf16(afrag(ah0), Bl0, a, 0,0,0);
            a = __builtin_amdgcn_mfma_f32_16x16x32_bf16(afrag(ah1), Bl1, a, 0,0,0);
            acc0[Mi] = a;
        }
        {
            const u4 ah0 = ap1[(     Mi)*64 + lane];
            const u4 al0 = ap1[( 4 + Mi)*64 + lane];
            const u4 ah1 = ap1[( 8 + Mi)*64 + lane];
            const u4 al1 = ap1[(12 + Mi)*64 + lane];
            f4 a = acc1[Mi];
            a = __builtin_amdgcn_mfma_f32_16x16x32_bf16(afrag(ah0), Bh0, a, 0,0,0);
            a = __builtin_amdgcn_mfma_f32_16x16x32_bf16(afrag(ah1), Bh1, a, 0,0,0);
            a = __builtin_amdgcn_mfma_f32_16x16x32_bf16(afrag(al0), Bh0, a, 0,0,0);
            a = __builtin_amdgcn_mfma_f32_16x16x32_bf16(afrag(al1), Bh1, a, 0,0,0);
            a = __builtin_amdgcn_mfma_f32_16x16x32_bf16(afrag(ah0), Bl0, a, 0,0,0);
            a = __builtin_amdgcn_mfma_f32_16x16x32_bf16(afrag(ah1), Bl1, a, 0,0,0);
            acc1[Mi] = a;
        }
    }
}

// prep0: all fp32 folds.
// blocks 0..63:  var=bid>>2, quarter: wgcf = log2e*W2@Wg (+ bgc on quarter 0)
// blocks 64..79: var=bid-64: wtpf = Wt@Wp, wt1f = Wt@W1, rpb = bt@Wp + bp
__global__ void prep0_kernel(const float* __restrict__ Wt, const float* __restrict__ W1,
                             const float* __restrict__ W2, const float* __restrict__ Wg,
                             const float* __restrict__ Wp,
                             const float* __restrict__ b2, const float* __restrict__ bg,
                             const float* __restrict__ bt, const float* __restrict__ bp,
                             float* __restrict__ wgcf, float* __restrict__ bgc,
                             float* __restrict__ wtpf, float* __restrict__ wt1f,
                             float* __restrict__ rpb) {
    __shared__ float sh[9216];
    const int tid = threadIdx.x;
    if (blockIdx.x < 64) {
        const int var = blockIdx.x >> 2;
        const int kb  = (blockIdx.x & 3) * 16;
        const float* wgsrc = Wg + var * 4096;
        #pragma unroll
        for (int i = 0; i < 16; ++i) sh[i*256 + tid] = wgsrc[i*256 + tid];
        __syncthreads();
        const int m  = tid & 63;
        const int ks = tid >> 6;            // 0..3
        const float* w2 = W2 + var * 4096;
        #pragma unroll
        for (int kk = 0; kk < 4; ++kk) {
            const int k = kb + ks * 4 + kk;
            float acc = 0.f;
            #pragma unroll 8
            for (int e = 0; e < 64; ++e) acc += w2[k*64 + e] * sh[e*64 + m];
            wgcf[(size_t)var*4096 + k*64 + m] = LOG2E * acc;
        }
        if ((blockIdx.x & 3) == 0 && tid < 64) {
            float acc = bg[var*64 + m];
            #pragma unroll 8
            for (int e = 0; e < 64; ++e) acc += b2[var*64 + e] * sh[e*64 + m];
            bgc[var*64 + m] = LOG2E * acc;
        }
        return;
    }
    const int var = blockIdx.x - 64;
    // sh: [0..4095] = Wp[var], [4096..8191] = W1[var], [8192..9215] = Wt[var]
    const float* wpsrc = Wp + var * 4096;
    const float* w1src = W1 + var * 4096;
    const float* wtsrc = Wt + var * 1024;
    #pragma unroll
    for (int i = 0; i < 16; ++i) sh[i*256 + tid]        = wpsrc[i*256 + tid];
    #pragma unroll
    for (int i = 0; i < 16; ++i) sh[4096 + i*256 + tid] = w1src[i*256 + tid];
    #pragma unroll
    for (int i = 0; i < 4; ++i)  sh[8192 + i*256 + tid] = wtsrc[i*256 + tid];
    __syncthreads();
    const int m  = tid & 63;
    const int vq = tid >> 6;                // 0..3
    #pragma unroll
    for (int vv = 0; vv < 4; ++vv) {
        const int v = vq*4 + vv;
        float ap = 0.f, a1 = 0.f;
        #pragma unroll 8
        for (int d = 0; d < 64; ++d) {
            const float w = sh[8192 + v*64 + d];
            ap += w * sh[d*64 + m];
            a1 += w * sh[4096 + d*64 + m];
        }
        wtpf[(size_t)var*1024 + v*64 + m] = ap;
        wt1f[(size_t)var*1024 + v*64 + m] = a1;
    }
    if (tid < 64) {
        float acc = bp[var*64 + tid];
        #pragma unroll 8
        for (int d = 0; d < 64; ++d) acc += bt[var*64 + d] * sh[d*64 + tid];
        rpb[var*64 + tid] = acc;
    }
}

// prep: pack (blocks 0..97) + context cpb1 (blocks 98..353).
__global__ void prep_kernel(const float* __restrict__ W2, const float* __restrict__ wgcf,
                            const float* __restrict__ wtpf, const float* __restrict__ wt1f,
                            const float* __restrict__ Ws,
                            const float* __restrict__ ctx, const float* __restrict__ Wctx,
                            const float* __restrict__ bt, const float* __restrict__ b1,
                            const float* __restrict__ W1,
                            u4* __restrict__ wtpp, u4* __restrict__ wt1p,
                            u4* __restrict__ bigp, u4* __restrict__ wsp,
                            float* __restrict__ cpb1) {
    if (blockIdx.x >= 98) {
        // cpb1[b][n][d] = (ctx@Wctx + bt)@W1 + b1  (fp32)
        __shared__ float cp[4][64];
        const int sub = threadIdx.x >> 6, d = threadIdx.x & 63;
        const int bn = (blockIdx.x - 98) * 4 + sub;
        const int b = bn >> 4, n = bn & 15;
        const float* __restrict__ wc = Wctx + n * DD * DD;
        const float* __restrict__ c  = ctx + b * DD;
        float acc = bt[n * DD + d];
        #pragma unroll 8
        for (int k = 0; k < DD; ++k) acc += c[k] * wc[k * DD + d];
        cp[sub][d] = acc;                   // cprojb row
        __syncthreads();
        const float* __restrict__ w1 = W1 + n * DD * DD;
        float r = b1[n * DD + d];
        #pragma unroll 8
        for (int k = 0; k < DD; ++k) r += cp[sub][k] * w1[k * DD + d];
        cpb1[bn * DD + d] = r;
        return;
    }
    const int t = blockIdx.x * 256 + threadIdx.x;
    if (t < 16384) {
        // bigp: mats 0=W2, 1=wgcf; per thread one (var,mat,c,Mi) h+l frag
        const int lane = t & 63, Mi = (t>>6)&3, c = (t>>8)&1, mat = (t>>9)&1, var = t>>10;
        const float* src = ((mat==0) ? W2 : wgcf) + (size_t)var*4096;
        const int m = 16*Mi + (lane&15), q = lane>>4;
        const int k0 = 32*c + 4*q;
        unsigned hb[8]; float lo[8];
        #pragma unroll
        for (int j = 0; j < 4; ++j) split1(src[(k0+j)*64+m],    hb[j],   lo[j]);
        #pragma unroll
        for (int j = 0; j < 4; ++j) split1(src[(k0+16+j)*64+m], hb[4+j], lo[4+j]);
        u4 hf, lf;
        hf.x = hb[0]|(hb[1]<<16); hf.y = hb[2]|(hb[3]<<16);
        hf.z = hb[4]|(hb[5]<<16); hf.w = hb[6]|(hb[7]<<16);
        lf.x = rnepk(lo[0],lo[1]); lf.y = rnepk(lo[2],lo[3]);
        lf.z = rnepk(lo[4],lo[5]); lf.w = rnepk(lo[6],lo[7]);
        u4* base = bigp + (size_t)((var*2+mat)*16)*64;
        base[((c*2+0)*4 + Mi)*64 + lane] = hf;
        base[((c*2+1)*4 + Mi)*64 + lane] = lf;
    } else if (t < 24576) {
        // wtpp / wt1p: K=16 [Wh|Wl] frags from wtpf / wt1f
        const int r = t - 16384;            // 0..8191
        const int which = r >> 12;          // 0: wtpf, 1: wt1f
        const int rr = r & 4095;
        const int lane = rr & 63, Mi = (rr>>6)&3, var = rr>>8;
        const int m = 16*Mi + (lane&15), k0 = 4*(lane>>4);
        const float* src = (which ? wt1f : wtpf) + (size_t)var*1024;
        f4 v;
        v.x = src[(k0+0)*64+m]; v.y = src[(k0+1)*64+m];
        v.z = src[(k0+2)*64+m]; v.w = src[(k0+3)*64+m];
        unsigned h0,h1,l0,l1; split4(v,h0,h1,l0,l1);
        u4 o; o.x=h0; o.y=h1; o.z=l0; o.w=l1;
        (which ? wt1p : wtpp)[(var*4+Mi)*64 + lane] = o;
    } else if (t < 25088) {
        // Ws: full-K chunks (c=0..7), h-frag + l-frag per thread
        const int r = t - 24576;
        const int lane = r & 63, c = r >> 6;
        const int n = lane & 15, q = lane >> 4;
        const int k0 = 32*c + 4*q;
        unsigned hb[8]; float lo[8];
        #pragma unroll
        for (int j = 0; j < 4; ++j) split1(Ws[(k0+j)*16+n],    hb[j],   lo[j]);
        #pragma unroll
        for (int j = 0; j < 4; ++j) split1(Ws[(k0+16+j)*16+n], hb[4+j], lo[4+j]);
        u4 hf, lf;
        hf.x = hb[0]|(hb[1]<<16); hf.y = hb[2]|(hb[3]<<16);
        hf.z = hb[4]|(hb[5]<<16); hf.w = hb[6]|(hb[7]<<16);
        lf.x = rnepk(lo[0],lo[1]); lf.y = rnepk(lo[2],lo[3]);
        lf.z = rnepk(lo[4],lo[5]); lf.w = rnepk(lo[6],lo[7]);
        wsp[(c*2+0)*64 + lane] = hf;
        wsp[(c*2+1)*64 + lane] = lf;
    }
}

// Main: block = 512 threads = 8 waves, 64 tokens; grid = 512 (R0 skeleton).
// REGISTER-CAP LEDGER: cap 128 + sel-in-LDS fits (R7-R9, VGPR 64); sel-in-regs
// spills (R6); cap<128 catastrophic (R1/R4). Never change.
// WALL LEDGER: work-removal (R7) -3us; wall-removal (R8) -11.5us, (R9) -37.5us.
// R10 LESSON (numerics): sumsq-LN (var = E[z2]-mu^2) cancels catastrophically
// in this mean-dominated workload -> absmax 0.016 FAIL (R9 two-pass = 0.0039).
// LayerNorm must stay TWO-PASS: reduce mu, then reduce sum((z-mu)^2).
// THIS ROUND: R10's wall-A pair fusion (17->13 walls, 2x MLP at fused wall,
// racc_b LDS stash, pre-zeroed RMW sel) + R9's two-pass LN restored.
#define PSEL_OFF 0          // 128 rows x 68 dw = 8704 dw
#define WSEL_OFF 8704       // 4 tq x 16 n x 17 = 1088 dw
#define RSP_OFF  9792       // racc_b stash: 128 rows x 68 dw = 8704 dw
#define SMEM_DW  18496      // 73984 B; 2 blocks/CU = 148KB <= 160KB

__device__ __forceinline__ void grn_tail(const int n, int lane, int qd, int l15, int tq,
        const u4* __restrict__ bigp, const float* __restrict__ b2,
        const float* __restrict__ bgc, const float* __restrict__ gamma_,
        const float* __restrict__ beta_, float* smem,
        const unsigned fh[4][2], const unsigned fl[4][2],
        const f4 racc[4], const int sbase) {
    f4 hacc[4], gacc[4];
    #pragma unroll
    for (int Mi = 0; Mi < 4; ++Mi) {
        hacc[Mi] = *(const f4*)(b2  + n*DD + 16*Mi + 4*qd);
        gacc[Mi] = *(const f4*)(bgc + n*DD + 16*Mi + 4*qd);
    }
    run_stage6_pair(bigp + (size_t)(n*2 + 0)*1024,
                    bigp + (size_t)(n*2 + 1)*1024, lane, fh, fl, hacc, gacc);
    // z = h2 * sigmoid + res; TWO-PASS LayerNorm (R10 lesson: no sumsq form)
    f4 z[4];
    float s = 0.f;
    #pragma unroll
    for (int Mi = 0; Mi < 4; ++Mi) {
        const f4 gv = gacc[Mi];
        z[Mi].x = hacc[Mi].x * __builtin_amdgcn_rcpf(1.f + __builtin_amdgcn_exp2f(-gv.x)) + racc[Mi].x;
        z[Mi].y = hacc[Mi].y * __builtin_amdgcn_rcpf(1.f + __builtin_amdgcn_exp2f(-gv.y)) + racc[Mi].y;
        z[Mi].z = hacc[Mi].z * __builtin_amdgcn_rcpf(1.f + __builtin_amdgcn_exp2f(-gv.z)) + racc[Mi].z;
        z[Mi].w = hacc[Mi].w * __builtin_amdgcn_rcpf(1.f + __builtin_amdgcn_exp2f(-gv.w)) + racc[Mi].w;
        s += z[Mi].x + z[Mi].y + z[Mi].z + z[Mi].w;
    }
    s += __shfl_xor(s, 16);
    s += __shfl_xor(s, 32);
    const float mu = s * (1.f/64.f);
    float q = 0.f;
    #pragma unroll
    for (int Mi = 0; Mi < 4; ++Mi) {
        float dx = z[Mi].x - mu; q += dx*dx;
        dx = z[Mi].y - mu; q += dx*dx;
        dx = z[Mi].z - mu; q += dx*dx;
        dx = z[Mi].w - mu; q += dx*dx;
    }
    q += __shfl_xor(q, 16);
    q += __shfl_xor(q, 32);
    const float rstd = rsqrtf(q*(1.f/64.f) + LN_EPS);
    const float wn = smem[WSEL_OFF + tq*272 + n*17 + l15];
    #pragma unroll
    for (int Mi = 0; Mi < 4; ++Mi) {
        const f4 gm = *(const f4*)(gamma_ + n*DD + 16*Mi + 4*qd);
        const f4 bb = *(const f4*)(beta_  + n*DD + 16*Mi + 4*qd);
        f4 cb;
        cb.x = wn*((z[Mi].x-mu)*rstd*gm.x + bb.x);
        cb.y = wn*((z[Mi].y-mu)*rstd*gm.y + bb.y);
        cb.z = wn*((z[Mi].z-mu)*rstd*gm.z + bb.z);
        cb.w = wn*((z[Mi].w-mu)*rstd*gm.w + bb.w);
        const f4 o = *(f4*)&smem[sbase + 16*Mi];
        *(f4*)&smem[sbase + 16*Mi] = o + cb;
    }
}

__global__ __launch_bounds__(512, 4)
void vsn_kernel(const float* __restrict__ inp,
                const u4* __restrict__ wtpp, const u4* __restrict__ wt1p,
                const u4* __restrict__ bigp, const u4* __restrict__ wsp,
                const float* __restrict__ b2, const float* __restrict__ bgc,
                const float* __restrict__ rpb, const float* __restrict__ cpb1,
                const float* __restrict__ gamma_, const float* __restrict__ beta_,
                const float* __restrict__ bs,
                float* __restrict__ out_sel, float* __restrict__ out_w) {
    __shared__ float smem[SMEM_DW];

    const int tid  = threadIdx.x;
    const int lane = tid & 63;
    const int wv   = tid >> 6;
    const int grp  = wv & 1;                    // var group (8 vars)
    const int tq   = wv >> 1;                   // token quarter (16 tokens)
    const int qd   = lane >> 4;
    const int l15  = lane & 15;
    const int tile0 = blockIdx.x * 64;
    const int b     = blockIdx.x >> 3;          // tile0 / NT
    const int tok0  = tile0 + tq * 16;

    const float* row = inp + (size_t)(tok0 + l15) * FF;   // my token's feature row

    // ---------------- logits via MFMA + softmax (per wave, 16 tokens) -------
    {
        f4 lacc = *(const f4*)(bs + 4*qd);      // n = 4*qd + reg
        #pragma unroll 4
        for (int c = 0; c < 8; ++c) {
            const u4 wh = wsp[(c*2+0)*64 + lane];
            const u4 wl = wsp[(c*2+1)*64 + lane];
            const f4 v1 = *(const f4*)(row + 32*c + 4*qd);
            const f4 v2 = *(const f4*)(row + 32*c + 16 + 4*qd);
            unsigned h0,h1,l0,l1,h2,h3,l2,l3;
            split4f(v1,h0,h1,l0,l1);
            split4f(v2,h2,h3,l2,l3);
            const bf8 Bh = mk_b4(h0,h1,h2,h3);
            const bf8 Bl = mk_b4(l0,l1,l2,l3);
            lacc = __builtin_amdgcn_mfma_f32_16x16x32_bf16(afrag(wh), Bh, lacc, 0,0,0);
            lacc = __builtin_amdgcn_mfma_f32_16x16x32_bf16(afrag(wl), Bh, lacc, 0,0,0);
            lacc = __builtin_amdgcn_mfma_f32_16x16x32_bf16(afrag(wh), Bl, lacc, 0,0,0);
        }
        float mx = fmaxf(fmaxf(lacc.x,lacc.y), fmaxf(lacc.z,lacc.w));
        mx = fmaxf(mx, __shfl_xor(mx, 16));
        mx = fmaxf(mx, __shfl_xor(mx, 32));
        float e0 = __expf(lacc.x-mx), e1 = __expf(lacc.y-mx);
        float e2 = __expf(lacc.z-mx), e3 = __expf(lacc.w-mx);
        float s = e0+e1+e2+e3;
        s += __shfl_xor(s, 16);
        s += __shfl_xor(s, 32);
        const float rs = __builtin_amdgcn_rcpf(s);
        e0 *= rs; e1 *= rs; e2 *= rs; e3 *= rs;
        const int base = WSEL_OFF + tq*272 + (4*qd)*17 + l15;
        smem[base + 0*17] = e0;
        smem[base + 1*17] = e1;
        smem[base + 2*17] = e2;
        smem[base + 3*17] = e3;
        if (grp == 0) {
            f4 o; o.x=e0; o.y=e1; o.z=e2; o.w=e3;
            *(f4*)(out_w + (size_t)(tok0 + l15)*16 + 4*qd) = o;
        }
    }

    // ---------------- per-variable GRN chains, var pairs (4 pairs/wave) -----
    const int sbase = PSEL_OFF + (grp*64 + tq*16 + l15)*68 + 4*qd;
    const int rspb  = RSP_OFF  + (grp*64 + tq*16 + l15)*68 + 4*qd;
    #pragma unroll
    for (int Mi = 0; Mi < 4; ++Mi) *(f4*)&smem[sbase + 16*Mi] = (f4)0.f;

    #pragma unroll 1
    for (int p = 0; p < 4; ++p) {
        const int na = grp*8 + 2*p;
        const int nb = na + 1;

        // ---- fused wall A: both vars' K=16 pairs off xv (one stall wall) ----
        f4 ra[4], ha[4], rb[4], hb4[4];
        #pragma unroll
        for (int Mi = 0; Mi < 4; ++Mi) {
            ra[Mi]  = *(const f4*)(rpb  + na*DD + 16*Mi + 4*qd);
            ha[Mi]  = *(const f4*)(cpb1 + (size_t)(b*NVAR+na)*DD + 16*Mi + 4*qd);
            rb[Mi]  = *(const f4*)(rpb  + nb*DD + 16*Mi + 4*qd);
            hb4[Mi] = *(const f4*)(cpb1 + (size_t)(b*NVAR+nb)*DD + 16*Mi + 4*qd);
        }
        {
            const f4 va = *(const f4*)(row + na*16 + 4*qd);
            const f4 vb = *(const f4*)(row + nb*16 + 4*qd);
            unsigned ah0,ah1,al0,al1, bh0,bh1,bl0,bl1;
            split4f(va, ah0,ah1,al0,al1);
            split4f(vb, bh0,bh1,bl0,bl1);
            const bf8 Bha = mk_bhh(ah0,ah1), Bla = mk_bl0(al0,al1);
            const bf8 Bhb = mk_bhh(bh0,bh1), Blb = mk_bl0(bl0,bl1);
            #pragma unroll
            for (int Mi = 0; Mi < 4; ++Mi) {
                const u4 w0 = wtpp[(na*4+Mi)*64 + lane];
                const u4 w1 = wt1p[(na*4+Mi)*64 + lane];
                const u4 w2 = wtpp[(nb*4+Mi)*64 + lane];
                const u4 w3 = wt1p[(nb*4+Mi)*64 + lane];
                ra[Mi]  = mfma2(ra[Mi],  afrag(w0), Bha, Bla);
                ha[Mi]  = mfma2(ha[Mi],  afrag(w1), Bha, Bla);
                rb[Mi]  = mfma2(rb[Mi],  afrag(w2), Bhb, Blb);
                hb4[Mi] = mfma2(hb4[Mi], afrag(w3), Bhb, Blb);
            }
        }
        // stash racc_b to LDS (lane-private; frees 16 regs across var a's tail)
        #pragma unroll
        for (int Mi = 0; Mi < 4; ++Mi)
            *(f4*)&smem[rspb + 16*Mi] = rb[Mi];

        // ELU + frags for both vars
        unsigned fha[4][2], fla[4][2], fhb[4][2], flb[4][2];
        elu4(ha);  acc_to_frags1(ha,  fha, fla);
        elu4(hb4); acc_to_frags1(hb4, fhb, flb);

        // ---- var a: wall B + epilogue ----
        grn_tail(na, lane, qd, l15, tq, bigp, b2, bgc, gamma_, beta_, smem,
                 fha, fla, ra, sbase);

        // ---- var b: reload racc_b, wall B + epilogue ----
        f4 rb2[4];
        #pragma unroll
        for (int Mi = 0; Mi < 4; ++Mi)
            rb2[Mi] = *(f4*)&smem[rspb + 16*Mi];
        grn_tail(nb, lane, qd, l15, tq, bigp, b2, bgc, gamma_, beta_, smem,
                 fhb, flb, rb2, sbase);
    }

    __syncthreads();
    {
        const int tokloc = tid >> 3;            // 0..63
        const int d0 = (tid & 7) * 8;
        const int rbase = PSEL_OFF + tokloc*68 + d0;
        const f4 a0 = *(f4*)&smem[rbase];
        const f4 a1 = *(f4*)&smem[rbase + 4];
        const f4 b0 = *(f4*)&smem[rbase + 64*68];
        const f4 b1v = *(f4*)&smem[rbase + 64*68 + 4];
        float* po = out_sel + (size_t)(tile0+tokloc)*DD + d0;
        *(f4*)po     = a0 + b0;
        *(f4*)(po+4) = a1 + b1v;
    }
}

extern "C" void kernel_launch(void* const* d_in, const int* in_sizes, int n_in,
                              void* d_out, int out_size, void* d_ws, size_t ws_size,
                              hipStream_t stream) {
    const float* inp  = (const float*)d_in[0];
    const float* ctx  = (const float*)d_in[1];
    const float* Wt   = (const float*)d_in[2];
    const float* bt   = (const float*)d_in[3];
    const float* Wctx = (const float*)d_in[4];
    const float* W1   = (const float*)d_in[5];
    const float* b1   = (const float*)d_in[6];
    const float* W2   = (const float*)d_in[7];
    const float* b2   = (const float*)d_in[8];
    const float* Wg   = (const float*)d_in[9];
    const float* bg   = (const float*)d_in[10];
    const float* Wp   = (const float*)d_in[11];
    const float* bp   = (const float*)d_in[12];
    const float* gm   = (const float*)d_in[13];
    const float* bt2  = (const float*)d_in[14];
    const float* Ws   = (const float*)d_in[15];
    const float* bs   = (const float*)d_in[16];

    float* out_sel = (float*)d_out;
    float* out_w   = out_sel + (size_t)BT * DD;

    char* ws = (char*)d_ws;
    float* cpb1 = (float*)(ws + CPB1_OFF);
    float* rpb  = (float*)(ws + RPB_OFF);
    u4* wtpp = (u4*)(ws + WTPP_OFF);
    u4* wt1p = (u4*)(ws + WT1P_OFF);
    u4* bigp = (u4*)(ws + BIGP_OFF);
    u4* wsp  = (u4*)(ws + WSP_OFF);
    float* bgc  = (float*)(ws + BGC_OFF);
    float* wgcf = (float*)(ws + WGCF_OFF);
    float* wtpf = (float*)(ws + WTPF_OFF);
    float* wt1f = (float*)(ws + WT1F_OFF);

    prep0_kernel<<<80, 256, 0, stream>>>(Wt, W1, W2, Wg, Wp, b2, bg, bt, bp,
                                         wgcf, bgc, wtpf, wt1f, rpb);
    prep_kernel<<<354, 256, 0, stream>>>(W2, wgcf, wtpf, wt1f, Ws, ctx, Wctx, bt, b1, W1,
                                         wtpp, wt1p, bigp, wsp, cpb1);
    vsn_kernel<<<BT / 64, 512, 0, stream>>>(inp, wtpp, wt1p, bigp, wsp,
                                            b2, bgc, rpb, cpb1, gm, bt2, bs,
                                            out_sel, out_w);
}

// Round 12
// 206.469 us; speedup vs baseline: 1.5839x; 1.5839x over previous
//
#include <hip/hip_runtime.h>

#define NB 64
#define NT 512
#define NVAR 16
#define VDIM 16
#define DD 64
#define FF 256
#define BT (NB*NT)
#define LN_EPS 1e-3f
#define LOG2E 1.4426950408889634f

typedef __attribute__((ext_vector_type(8))) short bf8;   // 8 bf16 = one MFMA A/B operand
typedef __attribute__((ext_vector_type(4))) float f4;
typedef __attribute__((ext_vector_type(4))) int i4;
typedef __attribute__((ext_vector_type(4))) unsigned u4;

// ---- ws layout (bytes) ----
// ALGEBRAIC FOLDS (all exact fp32 at prep):
//   rpb[n]     = bt@Wp + bp                      (res bias, per var)
//   cpb1[b][n] = (ctx@Wctx + bt)@W1 + b1         (h1 bias, per batch-var)
//   wtpf       = Wt@Wp, wt1f = Wt@W1             (K=16 mats off xv)
//   wgcf       = log2e*W2@Wg, bgc = log2e*(b2@Wg+bg)  (gate through W2)
// vsn walls per var: A) K=16 pair off xv  B) K=64 pair off h1.
#define CPB1_OFF   0                  // 64*16*64 f32 = 256KB
#define RPB_OFF    262144             // 16*64 f32 = 4KB
#define WTPP_OFF   266240             // packed Wt@Wp: 16v x 4Mi x 64 x 16B = 64KB
#define WT1P_OFF   331776             // packed Wt@W1: 64KB
#define BIGP_OFF   397312             // 2 mats x 16v x 16 frags x 64 x 16B = 512KB
#define WSP_OFF    921600             // 16 frags x 64 x 16B = 16KB
#define BGC_OFF    937984             // 16*64 f32 = 4KB
#define WGCF_OFF   942080             // wgc float intermediate 256KB
#define WTPF_OFF   1204224            // Wt@Wp float intermediate 64KB
#define WT1F_OFF   1269760            // Wt@W1 float intermediate 64KB
// bigp frag layout per var-mat (16 frags): idx = (c*2+hl)*4 + Mi ; mats 0=W2 1=wgcf

// ---- precise RNE split (prep-time only) ----
__device__ __forceinline__ void split1(float x, unsigned &hb, float &lo) {
    unsigned u = __builtin_bit_cast(unsigned, x);
    unsigned r = u + 0x7fffu + ((u >> 16) & 1u);
    hb = r >> 16;
    lo = x - __builtin_bit_cast(float, r & 0xffff0000u);
}
__device__ __forceinline__ unsigned rnepk(float x, float y) {
    unsigned a = __builtin_bit_cast(unsigned, x);
    unsigned b = __builtin_bit_cast(unsigned, y);
    a = a + 0x7fffu + ((a >> 16) & 1u);
    b = b + 0x7fffu + ((b >> 16) & 1u);
    return (a >> 16) | (b & 0xffff0000u);
}
__device__ __forceinline__ void split4(f4 v, unsigned &h0, unsigned &h1,
                                       unsigned &l0, unsigned &l1) {
    unsigned b0,b1,b2,b3; float q0,q1,q2,q3;
    split1(v.x,b0,q0); split1(v.y,b1,q1); split1(v.z,b2,q2); split1(v.w,b3,q3);
    h0 = b0 | (b1<<16); h1 = b2 | (b3<<16);
    l0 = rnepk(q0,q1); l1 = rnepk(q2,q3);
}
// ---- fast truncation split (hot path): hi = trunc(x), lo = trunc(x - hi) ----
__device__ __forceinline__ void split4f(f4 v, unsigned &h0, unsigned &h1,
                                        unsigned &l0, unsigned &l1) {
    unsigned a0 = __builtin_bit_cast(unsigned, v.x);
    unsigned a1 = __builtin_bit_cast(unsigned, v.y);
    unsigned a2 = __builtin_bit_cast(unsigned, v.z);
    unsigned a3 = __builtin_bit_cast(unsigned, v.w);
    unsigned m0 = a0 & 0xffff0000u, m1 = a1 & 0xffff0000u;
    unsigned m2 = a2 & 0xffff0000u, m3 = a3 & 0xffff0000u;
    h0 = (a0 >> 16) | m1;
    h1 = (a2 >> 16) | m3;
    float lx = v.x - __builtin_bit_cast(float, m0);
    float ly = v.y - __builtin_bit_cast(float, m1);
    float lz = v.z - __builtin_bit_cast(float, m2);
    float lw = v.w - __builtin_bit_cast(float, m3);
    l0 = (__builtin_bit_cast(unsigned, lx) >> 16) |
         (__builtin_bit_cast(unsigned, ly) & 0xffff0000u);
    l1 = (__builtin_bit_cast(unsigned, lz) >> 16) |
         (__builtin_bit_cast(unsigned, lw) & 0xffff0000u);
}
__device__ __forceinline__ bf8 afrag(u4 w) { return __builtin_bit_cast(bf8, w); }
__device__ __forceinline__ bf8 mk_b4(unsigned w0, unsigned w1, unsigned w2, unsigned w3) {
    i4 t; t.x = (int)w0; t.y = (int)w1; t.z = (int)w2; t.w = (int)w3;
    return __builtin_bit_cast(bf8, t);
}
// duplicated-B operands (K=16 stages)
__device__ __forceinline__ bf8 mk_bhh(unsigned h0, unsigned h1) {
    i4 t; t.x = (int)h0; t.y = (int)h1; t.z = (int)h0; t.w = (int)h1;
    return __builtin_bit_cast(bf8, t);
}
__device__ __forceinline__ bf8 mk_bl0(unsigned l0, unsigned l1) {
    i4 t; t.x = (int)l0; t.y = (int)l1; t.z = 0; t.w = 0;
    return __builtin_bit_cast(bf8, t);
}

__device__ __forceinline__ f4 mfma2(f4 acc, bf8 Af, bf8 Bh, bf8 Bl) {
    acc = __builtin_amdgcn_mfma_f32_16x16x32_bf16(Af, Bh, acc, 0,0,0);
    acc = __builtin_amdgcn_mfma_f32_16x16x32_bf16(Af, Bl, acc, 0,0,0);
    return acc;
}

// acc (C-layout) -> B-operand frags of the next stage (pure in-lane repack)
__device__ __forceinline__ void acc_to_frags1(const f4 acc[4],
        unsigned fh[4][2], unsigned fl[4][2]) {
    #pragma unroll
    for (int Ks = 0; Ks < 4; ++Ks)
        split4f(acc[Ks], fh[Ks][0], fh[Ks][1], fl[Ks][0], fl[Ks][1]);
}
// Paired 64x64 GEMM-stage, full-K: both mats consume the SAME B operands.
// 6 MFMAs per Mi per mat; terms Wh.xh + Wl.xh + Wh.xl (Wl.xl ~2^-16 dropped).
// setprio(1) wraps the MFMA cluster: waves here are barrier-free and drift out
// of phase, so prioritizing the MFMA-holding wave feeds the matrix pipe while
// other waves sit at load walls (attn-style win per the m191 ledger).
__device__ __forceinline__ void run_stage6_pair(const u4* __restrict__ ap0,
        const u4* __restrict__ ap1, int lane,
        const unsigned fh[4][2], const unsigned fl[4][2], f4 acc0[4], f4 acc1[4]) {
    const bf8 Bh0 = mk_b4(fh[0][0], fh[0][1], fh[1][0], fh[1][1]);
    const bf8 Bh1 = mk_b4(fh[2][0], fh[2][1], fh[3][0], fh[3][1]);
    const bf8 Bl0 = mk_b4(fl[0][0], fl[0][1], fl[1][0], fl[1][1]);
    const bf8 Bl1 = mk_b4(fl[2][0], fl[2][1], fl[3][0], fl[3][1]);
    __builtin_amdgcn_s_setprio(1);
    #pragma unroll
    for (int Mi = 0; Mi < 4; ++Mi) {
        {
            const u4 ah0 = ap0[(     Mi)*64 + lane];
            const u4 al0 = ap0[( 4 + Mi)*64 + lane];
            const u4 ah1 = ap0[( 8 + Mi)*64 + lane];
            const u4 al1 = ap0[(12 + Mi)*64 + lane];
            f4 a = acc0[Mi];
            a = __builtin_amdgcn_mfma_f32_16x16x32_bf16(afrag(ah0), Bh0, a, 0,0,0);
            a = __builtin_amdgcn_mfma_f32_16x16x32_bf16(afrag(ah1), Bh1, a, 0,0,0);
            a = __builtin_amdgcn_mfma_f32_16x16x32_bf16(afrag(al0), Bh0, a, 0,0,0);
            a = __builtin_amdgcn_mfma_f32_16x16x32_bf16(afrag(al1), Bh1, a, 0,0,0);
            a = __builtin_amdgcn_mfma_f32_16x16x32_bf16(afrag(ah0), Bl0, a, 0,0,0);
            a = __builtin_amdgcn_mfma_f32_16x16x32_bf16(afrag(ah1), Bl1, a, 0,0,0);
            acc0[Mi] = a;
        }
        {
            const u4 ah0 = ap1[(     Mi)*64 + lane];
            const u4 al0 = ap1[( 4 + Mi)*64 + lane];
            const u4 ah1 = ap1[( 8 + Mi)*64 + lane];
            const u4 al1 = ap1[(12 + Mi)*64 + lane];
            f4 a = acc1[Mi];
            a = __builtin_amdgcn_mfma_f32_16x16x32_bf16(afrag(ah0), Bh0, a, 0,0,0);
            a = __builtin_amdgcn_mfma_f32_16x16x32_bf16(afrag(ah1), Bh1, a, 0,0,0);
            a = __builtin_amdgcn_mfma_f32_16x16x32_bf16(afrag(al0), Bh0, a, 0,0,0);
            a = __builtin_amdgcn_mfma_f32_16x16x32_bf16(afrag(al1), Bh1, a, 0,0,0);
            a = __builtin_amdgcn_mfma_f32_16x16x32_bf16(afrag(ah0), Bl0, a, 0,0,0);
            a = __builtin_amdgcn_mfma_f32_16x16x32_bf16(afrag(ah1), Bl1, a, 0,0,0);
            acc1[Mi] = a;
        }
    }
    __builtin_amdgcn_s_setprio(0);
}

// prep0: all fp32 folds.
// blocks 0..63:  var=bid>>2, quarter: wgcf = log2e*W2@Wg (+ bgc on quarter 0)
// blocks 64..79: var=bid-64: wtpf = Wt@Wp, wt1f = Wt@W1, rpb = bt@Wp + bp
__global__ void prep0_kernel(const float* __restrict__ Wt, const float* __restrict__ W1,
                             const float* __restrict__ W2, const float* __restrict__ Wg,
                             const float* __restrict__ Wp,
                             const float* __restrict__ b2, const float* __restrict__ bg,
                             const float* __restrict__ bt, const float* __restrict__ bp,
                             float* __restrict__ wgcf, float* __restrict__ bgc,
                             float* __restrict__ wtpf, float* __restrict__ wt1f,
                             float* __restrict__ rpb) {
    __shared__ float sh[9216];
    const int tid = threadIdx.x;
    if (blockIdx.x < 64) {
        const int var = blockIdx.x >> 2;
        const int kb  = (blockIdx.x & 3) * 16;
        const float* wgsrc = Wg + var * 4096;
        #pragma unroll
        for (int i = 0; i < 16; ++i) sh[i*256 + tid] = wgsrc[i*256 + tid];
        __syncthreads();
        const int m  = tid & 63;
        const int ks = tid >> 6;            // 0..3
        const float* w2 = W2 + var * 4096;
        #pragma unroll
        for (int kk = 0; kk < 4; ++kk) {
            const int k = kb + ks * 4 + kk;
            float acc = 0.f;
            #pragma unroll 8
            for (int e = 0; e < 64; ++e) acc += w2[k*64 + e] * sh[e*64 + m];
            wgcf[(size_t)var*4096 + k*64 + m] = LOG2E * acc;
        }
        if ((blockIdx.x & 3) == 0 && tid < 64) {
            float acc = bg[var*64 + m];
            #pragma unroll 8
            for (int e = 0; e < 64; ++e) acc += b2[var*64 + e] * sh[e*64 + m];
            bgc[var*64 + m] = LOG2E * acc;
        }
        return;
    }
    const int var = blockIdx.x - 64;
    // sh: [0..4095] = Wp[var], [4096..8191] = W1[var], [8192..9215] = Wt[var]
    const float* wpsrc = Wp + var * 4096;
    const float* w1src = W1 + var * 4096;
    const float* wtsrc = Wt + var * 1024;
    #pragma unroll
    for (int i = 0; i < 16; ++i) sh[i*256 + tid]        = wpsrc[i*256 + tid];
    #pragma unroll
    for (int i = 0; i < 16; ++i) sh[4096 + i*256 + tid] = w1src[i*256 + tid];
    #pragma unroll
    for (int i = 0; i < 4; ++i)  sh[8192 + i*256 + tid] = wtsrc[i*256 + tid];
    __syncthreads();
    const int m  = tid & 63;
    const int vq = tid >> 6;                // 0..3
    #pragma unroll
    for (int vv = 0; vv < 4; ++vv) {
        const int v = vq*4 + vv;
        float ap = 0.f, a1 = 0.f;
        #pragma unroll 8
        for (int d = 0; d < 64; ++d) {
            const float w = sh[8192 + v*64 + d];
            ap += w * sh[d*64 + m];
            a1 += w * sh[4096 + d*64 + m];
        }
        wtpf[(size_t)var*1024 + v*64 + m] = ap;
        wt1f[(size_t)var*1024 + v*64 + m] = a1;
    }
    if (tid < 64) {
        float acc = bp[var*64 + tid];
        #pragma unroll 8
        for (int d = 0; d < 64; ++d) acc += bt[var*64 + d] * sh[d*64 + tid];
        rpb[var*64 + tid] = acc;
    }
}

// prep: pack (blocks 0..97) + context cpb1 (blocks 98..353).
__global__ void prep_kernel(const float* __restrict__ W2, const float* __restrict__ wgcf,
                            const float* __restrict__ wtpf, const float* __restrict__ wt1f,
                            const float* __restrict__ Ws,
                            const float* __restrict__ ctx, const float* __restrict__ Wctx,
                            const float* __restrict__ bt, const float* __restrict__ b1,
                            const float* __restrict__ W1,
                            u4* __restrict__ wtpp, u4* __restrict__ wt1p,
                            u4* __restrict__ bigp, u4* __restrict__ wsp,
                            float* __restrict__ cpb1) {
    if (blockIdx.x >= 98) {
        // cpb1[b][n][d] = (ctx@Wctx + bt)@W1 + b1  (fp32)
        __shared__ float cp[4][64];
        const int sub = threadIdx.x >> 6, d = threadIdx.x & 63;
        const int bn = (blockIdx.x - 98) * 4 + sub;
        const int b = bn >> 4, n = bn & 15;
        const float* __restrict__ wc = Wctx + n * DD * DD;
        const float* __restrict__ c  = ctx + b * DD;
        float acc = bt[n * DD + d];
        #pragma unroll 8
        for (int k = 0; k < DD; ++k) acc += c[k] * wc[k * DD + d];
        cp[sub][d] = acc;                   // cprojb row
        __syncthreads();
        const float* __restrict__ w1 = W1 + n * DD * DD;
        float r = b1[n * DD + d];
        #pragma unroll 8
        for (int k = 0; k < DD; ++k) r += cp[sub][k] * w1[k * DD + d];
        cpb1[bn * DD + d] = r;
        return;
    }
    const int t = blockIdx.x * 256 + threadIdx.x;
    if (t < 16384) {
        // bigp: mats 0=W2, 1=wgcf; per thread one (var,mat,c,Mi) h+l frag
        const int lane = t & 63, Mi = (t>>6)&3, c = (t>>8)&1, mat = (t>>9)&1, var = t>>10;
        const float* src = ((mat==0) ? W2 : wgcf) + (size_t)var*4096;
        const int m = 16*Mi + (lane&15), q = lane>>4;
        const int k0 = 32*c + 4*q;
        unsigned hb[8]; float lo[8];
        #pragma unroll
        for (int j = 0; j < 4; ++j) split1(src[(k0+j)*64+m],    hb[j],   lo[j]);
        #pragma unroll
        for (int j = 0; j < 4; ++j) split1(src[(k0+16+j)*64+m], hb[4+j], lo[4+j]);
        u4 hf, lf;
        hf.x = hb[0]|(hb[1]<<16); hf.y = hb[2]|(hb[3]<<16);
        hf.z = hb[4]|(hb[5]<<16); hf.w = hb[6]|(hb[7]<<16);
        lf.x = rnepk(lo[0],lo[1]); lf.y = rnepk(lo[2],lo[3]);
        lf.z = rnepk(lo[4],lo[5]); lf.w = rnepk(lo[6],lo[7]);
        u4* base = bigp + (size_t)((var*2+mat)*16)*64;
        base[((c*2+0)*4 + Mi)*64 + lane] = hf;
        base[((c*2+1)*4 + Mi)*64 + lane] = lf;
    } else if (t < 24576) {
        // wtpp / wt1p: K=16 [Wh|Wl] frags from wtpf / wt1f
        const int r = t - 16384;            // 0..8191
        const int which = r >> 12;          // 0: wtpf, 1: wt1f
        const int rr = r & 4095;
        const int lane = rr & 63, Mi = (rr>>6)&3, var = rr>>8;
        const int m = 16*Mi + (lane&15), k0 = 4*(lane>>4);
        const float* src = (which ? wt1f : wtpf) + (size_t)var*1024;
        f4 v;
        v.x = src[(k0+0)*64+m]; v.y = src[(k0+1)*64+m];
        v.z = src[(k0+2)*64+m]; v.w = src[(k0+3)*64+m];
        unsigned h0,h1,l0,l1; split4(v,h0,h1,l0,l1);
        u4 o; o.x=h0; o.y=h1; o.z=l0; o.w=l1;
        (which ? wt1p : wtpp)[(var*4+Mi)*64 + lane] = o;
    } else if (t < 25088) {
        // Ws: full-K chunks (c=0..7), h-frag + l-frag per thread
        const int r = t - 24576;
        const int lane = r & 63, c = r >> 6;
        const int n = lane & 15, q = lane >> 4;
        const int k0 = 32*c + 4*q;
        unsigned hb[8]; float lo[8];
        #pragma unroll
        for (int j = 0; j < 4; ++j) split1(Ws[(k0+j)*16+n],    hb[j],   lo[j]);
        #pragma unroll
        for (int j = 0; j < 4; ++j) split1(Ws[(k0+16+j)*16+n], hb[4+j], lo[4+j]);
        u4 hf, lf;
        hf.x = hb[0]|(hb[1]<<16); hf.y = hb[2]|(hb[3]<<16);
        hf.z = hb[4]|(hb[5]<<16); hf.w = hb[6]|(hb[7]<<16);
        lf.x = rnepk(lo[0],lo[1]); lf.y = rnepk(lo[2],lo[3]);
        lf.z = rnepk(lo[4],lo[5]); lf.w = rnepk(lo[6],lo[7]);
        wsp[(c*2+0)*64 + lane] = hf;
        wsp[(c*2+1)*64 + lane] = lf;
    }
}

// Main: block = 512 threads = 8 waves, 64 tokens; grid = 512 (R0 skeleton).
// REGISTER-CAP LEDGER: cap 128 + R9 body fits exactly (VGPR 64, no spill).
//   R6 (sel in regs): spill. R11 (+16 held frags for pair fusion): spill 453MB.
//   => ANY +16 long-lived regs over the R9 body spills; LDS > ~80KB/block
//   halves occupancy (2 stash regions don't fit). Pair fusion is closed at
//   cap 128; reopening it requires launch_bounds(512,3) = 170-reg cap at
//   3 waves/SIMD (documented next step if this round is flat).
// WALL LEDGER: work-removal -3us (R7); wall-removal -11.5 (R8), -37.5 (R9).
// R10 numerics: LayerNorm must stay TWO-PASS (sumsq cancels, absmax 4x).
// THIS ROUND: exact R9 body + s_setprio(1) around MFMA clusters (register-
// neutral; waves are barrier-free/out-of-phase -> attn-style scheduler win)
// + pre-zeroed always-RMW sel.
#define PSEL_OFF 0          // 128 rows x 68 dw = 8704 dw
#define WSEL_OFF 8704       // 4 tq x 16 n x 17 = 1088 dw
#define SMEM_DW  9792       // 39168 B; 2 blocks/CU = 78KB <= 160KB

__global__ __launch_bounds__(512, 4)
void vsn_kernel(const float* __restrict__ inp,
                const u4* __restrict__ wtpp, const u4* __restrict__ wt1p,
                const u4* __restrict__ bigp, const u4* __restrict__ wsp,
                const float* __restrict__ b2, const float* __restrict__ bgc,
                const float* __restrict__ rpb, const float* __restrict__ cpb1,
                const float* __restrict__ gamma_, const float* __restrict__ beta_,
                const float* __restrict__ bs,
                float* __restrict__ out_sel, float* __restrict__ out_w) {
    __shared__ float smem[SMEM_DW];

    const int tid  = threadIdx.x;
    const int lane = tid & 63;
    const int wv   = tid >> 6;
    const int grp  = wv & 1;                    // var group (8 vars)
    const int tq   = wv >> 1;                   // token quarter (16 tokens)
    const int qd   = lane >> 4;
    const int l15  = lane & 15;
    const int tile0 = blockIdx.x * 64;
    const int b     = blockIdx.x >> 3;          // tile0 / NT
    const int tok0  = tile0 + tq * 16;

    const float* row = inp + (size_t)(tok0 + l15) * FF;   // my token's feature row

    // ---------------- logits via MFMA + softmax (per wave, 16 tokens) -------
    {
        f4 lacc = *(const f4*)(bs + 4*qd);      // n = 4*qd + reg
        #pragma unroll 4
        for (int c = 0; c < 8; ++c) {
            const u4 wh = wsp[(c*2+0)*64 + lane];
            const u4 wl = wsp[(c*2+1)*64 + lane];
            const f4 v1 = *(const f4*)(row + 32*c + 4*qd);
            const f4 v2 = *(const f4*)(row + 32*c + 16 + 4*qd);
            unsigned h0,h1,l0,l1,h2,h3,l2,l3;
            split4f(v1,h0,h1,l0,l1);
            split4f(v2,h2,h3,l2,l3);
            const bf8 Bh = mk_b4(h0,h1,h2,h3);
            const bf8 Bl = mk_b4(l0,l1,l2,l3);
            lacc = __builtin_amdgcn_mfma_f32_16x16x32_bf16(afrag(wh), Bh, lacc, 0,0,0);
            lacc = __builtin_amdgcn_mfma_f32_16x16x32_bf16(afrag(wl), Bh, lacc, 0,0,0);
            lacc = __builtin_amdgcn_mfma_f32_16x16x32_bf16(afrag(wh), Bl, lacc, 0,0,0);
        }
        float mx = fmaxf(fmaxf(lacc.x,lacc.y), fmaxf(lacc.z,lacc.w));
        mx = fmaxf(mx, __shfl_xor(mx, 16));
        mx = fmaxf(mx, __shfl_xor(mx, 32));
        float e0 = __expf(lacc.x-mx), e1 = __expf(lacc.y-mx);
        float e2 = __expf(lacc.z-mx), e3 = __expf(lacc.w-mx);
        float s = e0+e1+e2+e3;
        s += __shfl_xor(s, 16);
        s += __shfl_xor(s, 32);
        const float rs = __builtin_amdgcn_rcpf(s);
        e0 *= rs; e1 *= rs; e2 *= rs; e3 *= rs;
        const int base = WSEL_OFF + tq*272 + (4*qd)*17 + l15;
        smem[base + 0*17] = e0;
        smem[base + 1*17] = e1;
        smem[base + 2*17] = e2;
        smem[base + 3*17] = e3;
        if (grp == 0) {
            f4 o; o.x=e0; o.y=e1; o.z=e2; o.w=e3;
            *(f4*)(out_w + (size_t)(tok0 + l15)*16 + 4*qd) = o;
        }
    }

    // ---------------- per-variable GRN chain (8 vars per wave) --------------
    const int sbase = PSEL_OFF + (grp*64 + tq*16 + l15)*68 + 4*qd;
    #pragma unroll
    for (int Mi = 0; Mi < 4; ++Mi) *(f4*)&smem[sbase + 16*Mi] = (f4)0.f;

    #pragma unroll 1
    for (int vi = 0; vi < 8; ++vi) {
        const int n = grp*8 + vi;
        unsigned fh[4][2], fl[4][2];

        // wall A (K=16 pair off xv): res = wtpf^T xv + rpb ; h1pre = wt1f^T xv + cpb1
        f4 racc[4], hacc[4];
        #pragma unroll
        for (int Mi = 0; Mi < 4; ++Mi) {
            racc[Mi] = *(const f4*)(rpb  + n*DD + 16*Mi + 4*qd);
            hacc[Mi] = *(const f4*)(cpb1 + (size_t)(b*NVAR+n)*DD + 16*Mi + 4*qd);
        }
        {
            const f4 v = *(const f4*)(row + n*16 + 4*qd);
            unsigned xh0,xh1,xl0,xl1;
            split4f(v, xh0, xh1, xl0, xl1);
            const bf8 Bh = mk_bhh(xh0, xh1);
            const bf8 Bl = mk_bl0(xl0, xl1);
            __builtin_amdgcn_s_setprio(1);
            #pragma unroll
            for (int Mi = 0; Mi < 4; ++Mi) {
                const u4 wA = wtpp[(n*4+Mi)*64 + lane];
                const u4 wB = wt1p[(n*4+Mi)*64 + lane];
                racc[Mi] = mfma2(racc[Mi], afrag(wA), Bh, Bl);
                hacc[Mi] = mfma2(hacc[Mi], afrag(wB), Bh, Bl);
            }
            __builtin_amdgcn_s_setprio(0);
        }
        #pragma unroll
        for (int Mi = 0; Mi < 4; ++Mi) {
            f4& v = hacc[Mi];
            v.x = v.x > 0.f ? v.x : (__expf(v.x)-1.f);
            v.y = v.y > 0.f ? v.y : (__expf(v.y)-1.f);
            v.z = v.z > 0.f ? v.z : (__expf(v.z)-1.f);
            v.w = v.w > 0.f ? v.w : (__expf(v.w)-1.f);
        }
        acc_to_frags1(hacc, fh, fl);   // h1 frags

        // wall B: h2 = W2^T h1 + b2 ; g' = wgcf^T h1 + bgc  (shared h1-frags)
        f4 gacc[4];
        #pragma unroll
        for (int Mi = 0; Mi < 4; ++Mi) {
            hacc[Mi] = *(const f4*)(b2  + n*DD + 16*Mi + 4*qd);
            gacc[Mi] = *(const f4*)(bgc + n*DD + 16*Mi + 4*qd);
        }
        run_stage6_pair(bigp + (size_t)(n*2 + 0)*1024,
                        bigp + (size_t)(n*2 + 1)*1024, lane, fh, fl, hacc, gacc);

        // z = h2 * rcp(1 + exp2(-g')) + res
        f4 z[4];
        float s = 0.f;
        #pragma unroll
        for (int Mi = 0; Mi < 4; ++Mi) {
            const f4 gv = gacc[Mi];
            z[Mi].x = hacc[Mi].x * __builtin_amdgcn_rcpf(1.f + __builtin_amdgcn_exp2f(-gv.x)) + racc[Mi].x;
            z[Mi].y = hacc[Mi].y * __builtin_amdgcn_rcpf(1.f + __builtin_amdgcn_exp2f(-gv.y)) + racc[Mi].y;
            z[Mi].z = hacc[Mi].z * __builtin_amdgcn_rcpf(1.f + __builtin_amdgcn_exp2f(-gv.z)) + racc[Mi].z;
            z[Mi].w = hacc[Mi].w * __builtin_amdgcn_rcpf(1.f + __builtin_amdgcn_exp2f(-gv.w)) + racc[Mi].w;
            s += z[Mi].x + z[Mi].y + z[Mi].z + z[Mi].w;
        }
        // TWO-PASS LayerNorm (R10 lesson: no sumsq form — cancellation)
        s += __shfl_xor(s, 16);
        s += __shfl_xor(s, 32);
        const float mu = s * (1.f/64.f);
        float q = 0.f;
        #pragma unroll
        for (int Mi = 0; Mi < 4; ++Mi) {
            float dx = z[Mi].x - mu; q += dx*dx;
            dx = z[Mi].y - mu; q += dx*dx;
            dx = z[Mi].z - mu; q += dx*dx;
            dx = z[Mi].w - mu; q += dx*dx;
        }
        q += __shfl_xor(q, 16);
        q += __shfl_xor(q, 32);
        const float rstd = rsqrtf(q*(1.f/64.f) + LN_EPS);

        const float wn = smem[WSEL_OFF + tq*272 + n*17 + l15];
        #pragma unroll
        for (int Mi = 0; Mi < 4; ++Mi) {
            const f4 gm = *(const f4*)(gamma_ + n*DD + 16*Mi + 4*qd);
            const f4 bb = *(const f4*)(beta_  + n*DD + 16*Mi + 4*qd);
            f4 cb;
            cb.x = wn*((z[Mi].x-mu)*rstd*gm.x + bb.x);
            cb.y = wn*((z[Mi].y-mu)*rstd*gm.y + bb.y);
            cb.z = wn*((z[Mi].z-mu)*rstd*gm.z + bb.z);
            cb.w = wn*((z[Mi].w-mu)*rstd*gm.w + bb.w);
            const f4 o = *(f4*)&smem[sbase + 16*Mi];
            *(f4*)&smem[sbase + 16*Mi] = o + cb;
        }
    }

    __syncthreads();
    {
        const int tokloc = tid >> 3;            // 0..63
        const int d0 = (tid & 7) * 8;
        const int rbase = PSEL_OFF + tokloc*68 + d0;
        const f4 a0 = *(f4*)&smem[rbase];
        const f4 a1 = *(f4*)&smem[rbase + 4];
        const f4 b0 = *(f4*)&smem[rbase + 64*68];
        const f4 b1v = *(f4*)&smem[rbase + 64*68 + 4];
        float* po = out_sel + (size_t)(tile0+tokloc)*DD + d0;
        *(f4*)po     = a0 + b0;
        *(f4*)(po+4) = a1 + b1v;
    }
}

extern "C" void kernel_launch(void* const* d_in, const int* in_sizes, int n_in,
                              void* d_out, int out_size, void* d_ws, size_t ws_size,
                              hipStream_t stream) {
    const float* inp  = (const float*)d_in[0];
    const float* ctx  = (const float*)d_in[1];
    const float* Wt   = (const float*)d_in[2];
    const float* bt   = (const float*)d_in[3];
    const float* Wctx = (const float*)d_in[4];
    const float* W1   = (const float*)d_in[5];
    const float* b1   = (const float*)d_in[6];
    const float* W2   = (const float*)d_in[7];
    const float* b2   = (const float*)d_in[8];
    const float* Wg   = (const float*)d_in[9];
    const float* bg   = (const float*)d_in[10];
    const float* Wp   = (const float*)d_in[11];
    const float* bp   = (const float*)d_in[12];
    const float* gm   = (const float*)d_in[13];
    const float* bt2  = (const float*)d_in[14];
    const float* Ws   = (const float*)d_in[15];
    const float* bs   = (const float*)d_in[16];

    float* out_sel = (float*)d_out;
    float* out_w   = out_sel + (size_t)BT * DD;

    char* ws = (char*)d_ws;
    float* cpb1 = (float*)(ws + CPB1_OFF);
    float* rpb  = (float*)(ws + RPB_OFF);
    u4* wtpp = (u4*)(ws + WTPP_OFF);
    u4* wt1p = (u4*)(ws + WT1P_OFF);
    u4* bigp = (u4*)(ws + BIGP_OFF);
    u4* wsp  = (u4*)(ws + WSP_OFF);
    float* bgc  = (float*)(ws + BGC_OFF);
    float* wgcf = (float*)(ws + WGCF_OFF);
    float* wtpf = (float*)(ws + WTPF_OFF);
    float* wt1f = (float*)(ws + WT1F_OFF);

    prep0_kernel<<<80, 256, 0, stream>>>(Wt, W1, W2, Wg, Wp, b2, bg, bt, bp,
                                         wgcf, bgc, wtpf, wt1f, rpb);
    prep_kernel<<<354, 256, 0, stream>>>(W2, wgcf, wtpf, wt1f, Ws, ctx, Wctx, bt, b1, W1,
                                         wtpp, wt1p, bigp, wsp, cpb1);
    vsn_kernel<<<BT / 64, 512, 0, stream>>>(inp, wtpp, wt1p, bigp, wsp,
                                            b2, bgc, rpb, cpb1, gm, bt2, bs,
                                            out_sel, out_w);
}

// Round 13
// 193.200 us; speedup vs baseline: 1.6927x; 1.0687x over previous
//
#include <hip/hip_runtime.h>

#define NB 64
#define NT 512
#define NVAR 16
#define VDIM 16
#define DD 64
#define FF 256
#define BT (NB*NT)
#define LN_EPS 1e-3f
#define LOG2E 1.4426950408889634f

typedef __attribute__((ext_vector_type(8))) short bf8;   // 8 bf16 = one MFMA A/B operand
typedef __attribute__((ext_vector_type(4))) float f4;
typedef __attribute__((ext_vector_type(4))) int i4;
typedef __attribute__((ext_vector_type(4))) unsigned u4;

// ---- ws layout (bytes) ----
// ALGEBRAIC FOLDS (all exact fp32 at prep):
//   rpb[n]     = bt@Wp + bp                      (res bias, per var)
//   cpb1[b][n] = (ctx@Wctx + bt)@W1 + b1         (h1 bias, per batch-var)
//   wtpf       = Wt@Wp, wt1f = Wt@W1             (K=16 mats off xv)
//   wgcf       = log2e*W2@Wg, bgc = log2e*(b2@Wg+bg)  (gate through W2)
// vsn walls per var: A) K=16 pair off xv  B) K=64 pair off h1.
#define CPB1_OFF   0                  // 64*16*64 f32 = 256KB
#define RPB_OFF    262144             // 16*64 f32 = 4KB
#define WTPP_OFF   266240             // packed Wt@Wp: 16v x 4Mi x 64 x 16B = 64KB
#define WT1P_OFF   331776             // packed Wt@W1: 64KB
#define BIGP_OFF   397312             // 2 mats x 16v x 16 frags x 64 x 16B = 512KB
#define WSP_OFF    921600             // 16 frags x 64 x 16B = 16KB
#define BGC_OFF    937984             // 16*64 f32 = 4KB
#define WGCF_OFF   942080             // wgc float intermediate 256KB
#define WTPF_OFF   1204224            // Wt@Wp float intermediate 64KB
#define WT1F_OFF   1269760            // Wt@W1 float intermediate 64KB
// bigp frag layout per var-mat (16 frags): idx = (c*2+hl)*4 + Mi ; mats 0=W2 1=wgcf

// ---- precise RNE split (prep-time only) ----
__device__ __forceinline__ void split1(float x, unsigned &hb, float &lo) {
    unsigned u = __builtin_bit_cast(unsigned, x);
    unsigned r = u + 0x7fffu + ((u >> 16) & 1u);
    hb = r >> 16;
    lo = x - __builtin_bit_cast(float, r & 0xffff0000u);
}
__device__ __forceinline__ unsigned rnepk(float x, float y) {
    unsigned a = __builtin_bit_cast(unsigned, x);
    unsigned b = __builtin_bit_cast(unsigned, y);
    a = a + 0x7fffu + ((a >> 16) & 1u);
    b = b + 0x7fffu + ((b >> 16) & 1u);
    return (a >> 16) | (b & 0xffff0000u);
}
__device__ __forceinline__ void split4(f4 v, unsigned &h0, unsigned &h1,
                                       unsigned &l0, unsigned &l1) {
    unsigned b0,b1,b2,b3; float q0,q1,q2,q3;
    split1(v.x,b0,q0); split1(v.y,b1,q1); split1(v.z,b2,q2); split1(v.w,b3,q3);
    h0 = b0 | (b1<<16); h1 = b2 | (b3<<16);
    l0 = rnepk(q0,q1); l1 = rnepk(q2,q3);
}
// ---- fast truncation split (hot path): hi = trunc(x), lo = trunc(x - hi) ----
__device__ __forceinline__ void split4f(f4 v, unsigned &h0, unsigned &h1,
                                        unsigned &l0, unsigned &l1) {
    unsigned a0 = __builtin_bit_cast(unsigned, v.x);
    unsigned a1 = __builtin_bit_cast(unsigned, v.y);
    unsigned a2 = __builtin_bit_cast(unsigned, v.z);
    unsigned a3 = __builtin_bit_cast(unsigned, v.w);
    unsigned m0 = a0 & 0xffff0000u, m1 = a1 & 0xffff0000u;
    unsigned m2 = a2 & 0xffff0000u, m3 = a3 & 0xffff0000u;
    h0 = (a0 >> 16) | m1;
    h1 = (a2 >> 16) | m3;
    float lx = v.x - __builtin_bit_cast(float, m0);
    float ly = v.y - __builtin_bit_cast(float, m1);
    float lz = v.z - __builtin_bit_cast(float, m2);
    float lw = v.w - __builtin_bit_cast(float, m3);
    l0 = (__builtin_bit_cast(unsigned, lx) >> 16) |
         (__builtin_bit_cast(unsigned, ly) & 0xffff0000u);
    l1 = (__builtin_bit_cast(unsigned, lz) >> 16) |
         (__builtin_bit_cast(unsigned, lw) & 0xffff0000u);
}
__device__ __forceinline__ bf8 afrag(u4 w) { return __builtin_bit_cast(bf8, w); }
__device__ __forceinline__ bf8 mk_b4(unsigned w0, unsigned w1, unsigned w2, unsigned w3) {
    i4 t; t.x = (int)w0; t.y = (int)w1; t.z = (int)w2; t.w = (int)w3;
    return __builtin_bit_cast(bf8, t);
}
// duplicated-B operands (K=16 stages)
__device__ __forceinline__ bf8 mk_bhh(unsigned h0, unsigned h1) {
    i4 t; t.x = (int)h0; t.y = (int)h1; t.z = (int)h0; t.w = (int)h1;
    return __builtin_bit_cast(bf8, t);
}
__device__ __forceinline__ bf8 mk_bl0(unsigned l0, unsigned l1) {
    i4 t; t.x = (int)l0; t.y = (int)l1; t.z = 0; t.w = 0;
    return __builtin_bit_cast(bf8, t);
}

__device__ __forceinline__ f4 mfma2(f4 acc, bf8 Af, bf8 Bh, bf8 Bl) {
    acc = __builtin_amdgcn_mfma_f32_16x16x32_bf16(Af, Bh, acc, 0,0,0);
    acc = __builtin_amdgcn_mfma_f32_16x16x32_bf16(Af, Bl, acc, 0,0,0);
    return acc;
}

// acc (C-layout) -> B-operand frags of the next stage (pure in-lane repack)
__device__ __forceinline__ void acc_to_frags1(const f4 acc[4],
        unsigned fh[4][2], unsigned fl[4][2]) {
    #pragma unroll
    for (int Ks = 0; Ks < 4; ++Ks)
        split4f(acc[Ks], fh[Ks][0], fh[Ks][1], fl[Ks][0], fl[Ks][1]);
}
// Paired 64x64 GEMM-stage, full-K: both mats consume the SAME B operands.
// 6 MFMAs per Mi per mat; terms Wh.xh + Wl.xh + Wh.xl (Wl.xl ~2^-16 dropped).
// NOTE (R12): do NOT wrap these in s_setprio — measured +17% regression
// (load-wave starvation + live-range extension -> 53MB scratch).
__device__ __forceinline__ void run_stage6_pair(const u4* __restrict__ ap0,
        const u4* __restrict__ ap1, int lane,
        const unsigned fh[4][2], const unsigned fl[4][2], f4 acc0[4], f4 acc1[4]) {
    const bf8 Bh0 = mk_b4(fh[0][0], fh[0][1], fh[1][0], fh[1][1]);
    const bf8 Bh1 = mk_b4(fh[2][0], fh[2][1], fh[3][0], fh[3][1]);
    const bf8 Bl0 = mk_b4(fl[0][0], fl[0][1], fl[1][0], fl[1][1]);
    const bf8 Bl1 = mk_b4(fl[2][0], fl[2][1], fl[3][0], fl[3][1]);
    #pragma unroll
    for (int Mi = 0; Mi < 4; ++Mi) {
        {
            const u4 ah0 = ap0[(     Mi)*64 + lane];
            const u4 al0 = ap0[( 4 + Mi)*64 + lane];
            const u4 ah1 = ap0[( 8 + Mi)*64 + lane];
            const u4 al1 = ap0[(12 + Mi)*64 + lane];
            f4 a = acc0[Mi];
            a = __builtin_amdgcn_mfma_f32_16x16x32_bf16(afrag(ah0), Bh0, a, 0,0,0);
            a = __builtin_amdgcn_mfma_f32_16x16x32_bf16(afrag(ah1), Bh1, a, 0,0,0);
            a = __builtin_amdgcn_mfma_f32_16x16x32_bf16(afrag(al0), Bh0, a, 0,0,0);
            a = __builtin_amdgcn_mfma_f32_16x16x32_bf16(afrag(al1), Bh1, a, 0,0,0);
            a = __builtin_amdgcn_mfma_f32_16x16x32_bf16(afrag(ah0), Bl0, a, 0,0,0);
            a = __builtin_amdgcn_mfma_f32_16x16x32_bf16(afrag(ah1), Bl1, a, 0,0,0);
            acc0[Mi] = a;
        }
        {
            const u4 ah0 = ap1[(     Mi)*64 + lane];
            const u4 al0 = ap1[( 4 + Mi)*64 + lane];
            const u4 ah1 = ap1[( 8 + Mi)*64 + lane];
            const u4 al1 = ap1[(12 + Mi)*64 + lane];
            f4 a = acc1[Mi];
            a = __builtin_amdgcn_mfma_f32_16x16x32_bf16(afrag(ah0), Bh0, a, 0,0,0);
            a = __builtin_amdgcn_mfma_f32_16x16x32_bf16(afrag(ah1), Bh1, a, 0,0,0);
            a = __builtin_amdgcn_mfma_f32_16x16x32_bf16(afrag(al0), Bh0, a, 0,0,0);
            a = __builtin_amdgcn_mfma_f32_16x16x32_bf16(afrag(al1), Bh1, a, 0,0,0);
            a = __builtin_amdgcn_mfma_f32_16x16x32_bf16(afrag(ah0), Bl0, a, 0,0,0);
            a = __builtin_amdgcn_mfma_f32_16x16x32_bf16(afrag(ah1), Bl1, a, 0,0,0);
            acc1[Mi] = a;
        }
    }
}

// prep0: all fp32 folds.
// blocks 0..63:  var=bid>>2, quarter: wgcf = log2e*W2@Wg (+ bgc on quarter 0)
// blocks 64..79: var=bid-64: wtpf = Wt@Wp, wt1f = Wt@W1, rpb = bt@Wp + bp
__global__ void prep0_kernel(const float* __restrict__ Wt, const float* __restrict__ W1,
                             const float* __restrict__ W2, const float* __restrict__ Wg,
                             const float* __restrict__ Wp,
                             const float* __restrict__ b2, const float* __restrict__ bg,
                             const float* __restrict__ bt, const float* __restrict__ bp,
                             float* __restrict__ wgcf, float* __restrict__ bgc,
                             float* __restrict__ wtpf, float* __restrict__ wt1f,
                             float* __restrict__ rpb) {
    __shared__ float sh[9216];
    const int tid = threadIdx.x;
    if (blockIdx.x < 64) {
        const int var = blockIdx.x >> 2;
        const int kb  = (blockIdx.x & 3) * 16;
        const float* wgsrc = Wg + var * 4096;
        #pragma unroll
        for (int i = 0; i < 16; ++i) sh[i*256 + tid] = wgsrc[i*256 + tid];
        __syncthreads();
        const int m  = tid & 63;
        const int ks = tid >> 6;            // 0..3
        const float* w2 = W2 + var * 4096;
        #pragma unroll
        for (int kk = 0; kk < 4; ++kk) {
            const int k = kb + ks * 4 + kk;
            float acc = 0.f;
            #pragma unroll 8
            for (int e = 0; e < 64; ++e) acc += w2[k*64 + e] * sh[e*64 + m];
            wgcf[(size_t)var*4096 + k*64 + m] = LOG2E * acc;
        }
        if ((blockIdx.x & 3) == 0 && tid < 64) {
            float acc = bg[var*64 + m];
            #pragma unroll 8
            for (int e = 0; e < 64; ++e) acc += b2[var*64 + e] * sh[e*64 + m];
            bgc[var*64 + m] = LOG2E * acc;
        }
        return;
    }
    const int var = blockIdx.x - 64;
    // sh: [0..4095] = Wp[var], [4096..8191] = W1[var], [8192..9215] = Wt[var]
    const float* wpsrc = Wp + var * 4096;
    const float* w1src = W1 + var * 4096;
    const float* wtsrc = Wt + var * 1024;
    #pragma unroll
    for (int i = 0; i < 16; ++i) sh[i*256 + tid]        = wpsrc[i*256 + tid];
    #pragma unroll
    for (int i = 0; i < 16; ++i) sh[4096 + i*256 + tid] = w1src[i*256 + tid];
    #pragma unroll
    for (int i = 0; i < 4; ++i)  sh[8192 + i*256 + tid] = wtsrc[i*256 + tid];
    __syncthreads();
    const int m  = tid & 63;
    const int vq = tid >> 6;                // 0..3
    #pragma unroll
    for (int vv = 0; vv < 4; ++vv) {
        const int v = vq*4 + vv;
        float ap = 0.f, a1 = 0.f;
        #pragma unroll 8
        for (int d = 0; d < 64; ++d) {
            const float w = sh[8192 + v*64 + d];
            ap += w * sh[d*64 + m];
            a1 += w * sh[4096 + d*64 + m];
        }
        wtpf[(size_t)var*1024 + v*64 + m] = ap;
        wt1f[(size_t)var*1024 + v*64 + m] = a1;
    }
    if (tid < 64) {
        float acc = bp[var*64 + tid];
        #pragma unroll 8
        for (int d = 0; d < 64; ++d) acc += bt[var*64 + d] * sh[d*64 + tid];
        rpb[var*64 + tid] = acc;
    }
}

// prep: pack (blocks 0..97) + context cpb1 (blocks 98..353).
__global__ void prep_kernel(const float* __restrict__ W2, const float* __restrict__ wgcf,
                            const float* __restrict__ wtpf, const float* __restrict__ wt1f,
                            const float* __restrict__ Ws,
                            const float* __restrict__ ctx, const float* __restrict__ Wctx,
                            const float* __restrict__ bt, const float* __restrict__ b1,
                            const float* __restrict__ W1,
                            u4* __restrict__ wtpp, u4* __restrict__ wt1p,
                            u4* __restrict__ bigp, u4* __restrict__ wsp,
                            float* __restrict__ cpb1) {
    if (blockIdx.x >= 98) {
        // cpb1[b][n][d] = (ctx@Wctx + bt)@W1 + b1  (fp32)
        __shared__ float cp[4][64];
        const int sub = threadIdx.x >> 6, d = threadIdx.x & 63;
        const int bn = (blockIdx.x - 98) * 4 + sub;
        const int b = bn >> 4, n = bn & 15;
        const float* __restrict__ wc = Wctx + n * DD * DD;
        const float* __restrict__ c  = ctx + b * DD;
        float acc = bt[n * DD + d];
        #pragma unroll 8
        for (int k = 0; k < DD; ++k) acc += c[k] * wc[k * DD + d];
        cp[sub][d] = acc;                   // cprojb row
        __syncthreads();
        const float* __restrict__ w1 = W1 + n * DD * DD;
        float r = b1[n * DD + d];
        #pragma unroll 8
        for (int k = 0; k < DD; ++k) r += cp[sub][k] * w1[k * DD + d];
        cpb1[bn * DD + d] = r;
        return;
    }
    const int t = blockIdx.x * 256 + threadIdx.x;
    if (t < 16384) {
        // bigp: mats 0=W2, 1=wgcf; per thread one (var,mat,c,Mi) h+l frag
        const int lane = t & 63, Mi = (t>>6)&3, c = (t>>8)&1, mat = (t>>9)&1, var = t>>10;
        const float* src = ((mat==0) ? W2 : wgcf) + (size_t)var*4096;
        const int m = 16*Mi + (lane&15), q = lane>>4;
        const int k0 = 32*c + 4*q;
        unsigned hb[8]; float lo[8];
        #pragma unroll
        for (int j = 0; j < 4; ++j) split1(src[(k0+j)*64+m],    hb[j],   lo[j]);
        #pragma unroll
        for (int j = 0; j < 4; ++j) split1(src[(k0+16+j)*64+m], hb[4+j], lo[4+j]);
        u4 hf, lf;
        hf.x = hb[0]|(hb[1]<<16); hf.y = hb[2]|(hb[3]<<16);
        hf.z = hb[4]|(hb[5]<<16); hf.w = hb[6]|(hb[7]<<16);
        lf.x = rnepk(lo[0],lo[1]); lf.y = rnepk(lo[2],lo[3]);
        lf.z = rnepk(lo[4],lo[5]); lf.w = rnepk(lo[6],lo[7]);
        u4* base = bigp + (size_t)((var*2+mat)*16)*64;
        base[((c*2+0)*4 + Mi)*64 + lane] = hf;
        base[((c*2+1)*4 + Mi)*64 + lane] = lf;
    } else if (t < 24576) {
        // wtpp / wt1p: K=16 [Wh|Wl] frags from wtpf / wt1f
        const int r = t - 16384;            // 0..8191
        const int which = r >> 12;          // 0: wtpf, 1: wt1f
        const int rr = r & 4095;
        const int lane = rr & 63, Mi = (rr>>6)&3, var = rr>>8;
        const int m = 16*Mi + (lane&15), k0 = 4*(lane>>4);
        const float* src = (which ? wt1f : wtpf) + (size_t)var*1024;
        f4 v;
        v.x = src[(k0+0)*64+m]; v.y = src[(k0+1)*64+m];
        v.z = src[(k0+2)*64+m]; v.w = src[(k0+3)*64+m];
        unsigned h0,h1,l0,l1; split4(v,h0,h1,l0,l1);
        u4 o; o.x=h0; o.y=h1; o.z=l0; o.w=l1;
        (which ? wt1p : wtpp)[(var*4+Mi)*64 + lane] = o;
    } else if (t < 25088) {
        // Ws: full-K chunks (c=0..7), h-frag + l-frag per thread
        const int r = t - 24576;
        const int lane = r & 63, c = r >> 6;
        const int n = lane & 15, q = lane >> 4;
        const int k0 = 32*c + 4*q;
        unsigned hb[8]; float lo[8];
        #pragma unroll
        for (int j = 0; j < 4; ++j) split1(Ws[(k0+j)*16+n],    hb[j],   lo[j]);
        #pragma unroll
        for (int j = 0; j < 4; ++j) split1(Ws[(k0+16+j)*16+n], hb[4+j], lo[4+j]);
        u4 hf, lf;
        hf.x = hb[0]|(hb[1]<<16); hf.y = hb[2]|(hb[3]<<16);
        hf.z = hb[4]|(hb[5]<<16); hf.w = hb[6]|(hb[7]<<16);
        lf.x = rnepk(lo[0],lo[1]); lf.y = rnepk(lo[2],lo[3]);
        lf.z = rnepk(lo[4],lo[5]); lf.w = rnepk(lo[6],lo[7]);
        wsp[(c*2+0)*64 + lane] = hf;
        wsp[(c*2+1)*64 + lane] = lf;
    }
}

// Main: block = 512 threads = 8 waves, 64 tokens; grid = 512 (R0 skeleton).
// THIS IS THE VERIFIED SESSION OPTIMUM (R9: vsn 91.5us, total 193us, absmax
// 0.0039). Every post-R9 branch is CLOSED with a measured mechanism:
//   R10 sumsq-LN        -> absmax 4x FAIL (cancellation; LN must be two-pass)
//   R11 pair-fusion@128  -> +16 held regs spill 453MB (R9 body fits EXACTLY)
//   R12 s_setprio(MFMA)  -> +17% (load-wave starvation + 53MB scratch)
// REGISTER-CAP LEDGER: cap 128 + sel-in-LDS fits; sel-in-regs or +16 regs
// spills; cap<128 catastrophic. WALL LEDGER: work-removal ~free, wall-removal
// is the lever (17 walls/wave here: logits + 8x{A,B}).
// Open next experiment (untested): launch_bounds(512,3) = cap 170 to reopen
// pair fusion fully in-reg at 3 waves/SIMD (-12% occupancy for -23% walls).
#define PSEL_OFF 0          // 128 rows x 68 dw = 8704 dw
#define WSEL_OFF 8704       // 4 tq x 16 n x 17 = 1088 dw
#define SMEM_DW  9792       // 39168 B; 2 blocks/CU = 78KB <= 160KB

__global__ __launch_bounds__(512, 4)
void vsn_kernel(const float* __restrict__ inp,
                const u4* __restrict__ wtpp, const u4* __restrict__ wt1p,
                const u4* __restrict__ bigp, const u4* __restrict__ wsp,
                const float* __restrict__ b2, const float* __restrict__ bgc,
                const float* __restrict__ rpb, const float* __restrict__ cpb1,
                const float* __restrict__ gamma_, const float* __restrict__ beta_,
                const float* __restrict__ bs,
                float* __restrict__ out_sel, float* __restrict__ out_w) {
    __shared__ float smem[SMEM_DW];

    const int tid  = threadIdx.x;
    const int lane = tid & 63;
    const int wv   = tid >> 6;
    const int grp  = wv & 1;                    // var group (8 vars)
    const int tq   = wv >> 1;                   // token quarter (16 tokens)
    const int qd   = lane >> 4;
    const int l15  = lane & 15;
    const int tile0 = blockIdx.x * 64;
    const int b     = blockIdx.x >> 3;          // tile0 / NT
    const int tok0  = tile0 + tq * 16;

    const float* row = inp + (size_t)(tok0 + l15) * FF;   // my token's feature row

    // ---------------- logits via MFMA + softmax (per wave, 16 tokens) -------
    {
        f4 lacc = *(const f4*)(bs + 4*qd);      // n = 4*qd + reg
        #pragma unroll 4
        for (int c = 0; c < 8; ++c) {
            const u4 wh = wsp[(c*2+0)*64 + lane];
            const u4 wl = wsp[(c*2+1)*64 + lane];
            const f4 v1 = *(const f4*)(row + 32*c + 4*qd);
            const f4 v2 = *(const f4*)(row + 32*c + 16 + 4*qd);
            unsigned h0,h1,l0,l1,h2,h3,l2,l3;
            split4f(v1,h0,h1,l0,l1);
            split4f(v2,h2,h3,l2,l3);
            const bf8 Bh = mk_b4(h0,h1,h2,h3);
            const bf8 Bl = mk_b4(l0,l1,l2,l3);
            lacc = __builtin_amdgcn_mfma_f32_16x16x32_bf16(afrag(wh), Bh, lacc, 0,0,0);
            lacc = __builtin_amdgcn_mfma_f32_16x16x32_bf16(afrag(wl), Bh, lacc, 0,0,0);
            lacc = __builtin_amdgcn_mfma_f32_16x16x32_bf16(afrag(wh), Bl, lacc, 0,0,0);
        }
        float mx = fmaxf(fmaxf(lacc.x,lacc.y), fmaxf(lacc.z,lacc.w));
        mx = fmaxf(mx, __shfl_xor(mx, 16));
        mx = fmaxf(mx, __shfl_xor(mx, 32));
        float e0 = __expf(lacc.x-mx), e1 = __expf(lacc.y-mx);
        float e2 = __expf(lacc.z-mx), e3 = __expf(lacc.w-mx);
        float s = e0+e1+e2+e3;
        s += __shfl_xor(s, 16);
        s += __shfl_xor(s, 32);
        const float rs = __builtin_amdgcn_rcpf(s);
        e0 *= rs; e1 *= rs; e2 *= rs; e3 *= rs;
        const int base = WSEL_OFF + tq*272 + (4*qd)*17 + l15;
        smem[base + 0*17] = e0;
        smem[base + 1*17] = e1;
        smem[base + 2*17] = e2;
        smem[base + 3*17] = e3;
        if (grp == 0) {
            f4 o; o.x=e0; o.y=e1; o.z=e2; o.w=e3;
            *(f4*)(out_w + (size_t)(tok0 + l15)*16 + 4*qd) = o;
        }
    }

    // ---------------- per-variable GRN chain (8 vars per wave) --------------
    const int sbase = PSEL_OFF + (grp*64 + tq*16 + l15)*68 + 4*qd;

    #pragma unroll 1
    for (int vi = 0; vi < 8; ++vi) {
        const int n = grp*8 + vi;
        unsigned fh[4][2], fl[4][2];

        // wall A (K=16 pair off xv): res = wtpf^T xv + rpb ; h1pre = wt1f^T xv + cpb1
        f4 racc[4], hacc[4];
        #pragma unroll
        for (int Mi = 0; Mi < 4; ++Mi) {
            racc[Mi] = *(const f4*)(rpb  + n*DD + 16*Mi + 4*qd);
            hacc[Mi] = *(const f4*)(cpb1 + (size_t)(b*NVAR+n)*DD + 16*Mi + 4*qd);
        }
        {
            const f4 v = *(const f4*)(row + n*16 + 4*qd);
            unsigned xh0,xh1,xl0,xl1;
            split4f(v, xh0, xh1, xl0, xl1);
            const bf8 Bh = mk_bhh(xh0, xh1);
            const bf8 Bl = mk_bl0(xl0, xl1);
            #pragma unroll
            for (int Mi = 0; Mi < 4; ++Mi) {
                const u4 wA = wtpp[(n*4+Mi)*64 + lane];
                const u4 wB = wt1p[(n*4+Mi)*64 + lane];
                racc[Mi] = mfma2(racc[Mi], afrag(wA), Bh, Bl);
                hacc[Mi] = mfma2(hacc[Mi], afrag(wB), Bh, Bl);
            }
        }
        #pragma unroll
        for (int Mi = 0; Mi < 4; ++Mi) {
            f4& v = hacc[Mi];
            v.x = v.x > 0.f ? v.x : (__expf(v.x)-1.f);
            v.y = v.y > 0.f ? v.y : (__expf(v.y)-1.f);
            v.z = v.z > 0.f ? v.z : (__expf(v.z)-1.f);
            v.w = v.w > 0.f ? v.w : (__expf(v.w)-1.f);
        }
        acc_to_frags1(hacc, fh, fl);   // h1 frags

        // wall B: h2 = W2^T h1 + b2 ; g' = wgcf^T h1 + bgc  (shared h1-frags)
        f4 gacc[4];
        #pragma unroll
        for (int Mi = 0; Mi < 4; ++Mi) {
            hacc[Mi] = *(const f4*)(b2  + n*DD + 16*Mi + 4*qd);
            gacc[Mi] = *(const f4*)(bgc + n*DD + 16*Mi + 4*qd);
        }
        run_stage6_pair(bigp + (size_t)(n*2 + 0)*1024,
                        bigp + (size_t)(n*2 + 1)*1024, lane, fh, fl, hacc, gacc);

        // z = h2 * rcp(1 + exp2(-g')) + res
        f4 z[4];
        #pragma unroll
        for (int Mi = 0; Mi < 4; ++Mi) {
            const f4 gv = gacc[Mi];
            z[Mi].x = hacc[Mi].x * __builtin_amdgcn_rcpf(1.f + __builtin_amdgcn_exp2f(-gv.x)) + racc[Mi].x;
            z[Mi].y = hacc[Mi].y * __builtin_amdgcn_rcpf(1.f + __builtin_amdgcn_exp2f(-gv.y)) + racc[Mi].y;
            z[Mi].z = hacc[Mi].z * __builtin_amdgcn_rcpf(1.f + __builtin_amdgcn_exp2f(-gv.z)) + racc[Mi].z;
            z[Mi].w = hacc[Mi].w * __builtin_amdgcn_rcpf(1.f + __builtin_amdgcn_exp2f(-gv.w)) + racc[Mi].w;
        }
        // TWO-PASS LayerNorm (R10 lesson: sumsq form cancels — keep two-pass)
        float s = 0.f;
        #pragma unroll
        for (int Mi = 0; Mi < 4; ++Mi) s += z[Mi].x + z[Mi].y + z[Mi].z + z[Mi].w;
        s += __shfl_xor(s, 16);
        s += __shfl_xor(s, 32);
        const float mu = s * (1.f/64.f);
        float q = 0.f;
        #pragma unroll
        for (int Mi = 0; Mi < 4; ++Mi) {
            float dx = z[Mi].x - mu; q += dx*dx;
            dx = z[Mi].y - mu; q += dx*dx;
            dx = z[Mi].z - mu; q += dx*dx;
            dx = z[Mi].w - mu; q += dx*dx;
        }
        q += __shfl_xor(q, 16);
        q += __shfl_xor(q, 32);
        const float rstd = rsqrtf(q*(1.f/64.f) + LN_EPS);

        const float wn = smem[WSEL_OFF + tq*272 + n*17 + l15];
        #pragma unroll
        for (int Mi = 0; Mi < 4; ++Mi) {
            const f4 gm = *(const f4*)(gamma_ + n*DD + 16*Mi + 4*qd);
            const f4 bb = *(const f4*)(beta_  + n*DD + 16*Mi + 4*qd);
            f4 cb;
            cb.x = wn*((z[Mi].x-mu)*rstd*gm.x + bb.x);
            cb.y = wn*((z[Mi].y-mu)*rstd*gm.y + bb.y);
            cb.z = wn*((z[Mi].z-mu)*rstd*gm.z + bb.z);
            cb.w = wn*((z[Mi].w-mu)*rstd*gm.w + bb.w);
            if (vi == 0) {
                *(f4*)&smem[sbase + 16*Mi] = cb;
            } else {
                const f4 o = *(f4*)&smem[sbase + 16*Mi];
                *(f4*)&smem[sbase + 16*Mi] = o + cb;
            }
        }
    }

    __syncthreads();
    {
        const int tokloc = tid >> 3;            // 0..63
        const int d0 = (tid & 7) * 8;
        const int rbase = PSEL_OFF + tokloc*68 + d0;
        const f4 a0 = *(f4*)&smem[rbase];
        const f4 a1 = *(f4*)&smem[rbase + 4];
        const f4 b0 = *(f4*)&smem[rbase + 64*68];
        const f4 b1v = *(f4*)&smem[rbase + 64*68 + 4];
        float* po = out_sel + (size_t)(tile0+tokloc)*DD + d0;
        *(f4*)po     = a0 + b0;
        *(f4*)(po+4) = a1 + b1v;
    }
}

extern "C" void kernel_launch(void* const* d_in, const int* in_sizes, int n_in,
                              void* d_out, int out_size, void* d_ws, size_t ws_size,
                              hipStream_t stream) {
    const float* inp  = (const float*)d_in[0];
    const float* ctx  = (const float*)d_in[1];
    const float* Wt   = (const float*)d_in[2];
    const float* bt   = (const float*)d_in[3];
    const float* Wctx = (const float*)d_in[4];
    const float* W1   = (const float*)d_in[5];
    const float* b1   = (const float*)d_in[6];
    const float* W2   = (const float*)d_in[7];
    const float* b2   = (const float*)d_in[8];
    const float* Wg   = (const float*)d_in[9];
    const float* bg   = (const float*)d_in[10];
    const float* Wp   = (const float*)d_in[11];
    const float* bp   = (const float*)d_in[12];
    const float* gm   = (const float*)d_in[13];
    const float* bt2  = (const float*)d_in[14];
    const float* Ws   = (const float*)d_in[15];
    const float* bs   = (const float*)d_in[16];

    float* out_sel = (float*)d_out;
    float* out_w   = out_sel + (size_t)BT * DD;

    char* ws = (char*)d_ws;
    float* cpb1 = (float*)(ws + CPB1_OFF);
    float* rpb  = (float*)(ws + RPB_OFF);
    u4* wtpp = (u4*)(ws + WTPP_OFF);
    u4* wt1p = (u4*)(ws + WT1P_OFF);
    u4* bigp = (u4*)(ws + BIGP_OFF);
    u4* wsp  = (u4*)(ws + WSP_OFF);
    float* bgc  = (float*)(ws + BGC_OFF);
    float* wgcf = (float*)(ws + WGCF_OFF);
    float* wtpf = (float*)(ws + WTPF_OFF);
    float* wt1f = (float*)(ws + WT1F_OFF);

    prep0_kernel<<<80, 256, 0, stream>>>(Wt, W1, W2, Wg, Wp, b2, bg, bt, bp,
                                         wgcf, bgc, wtpf, wt1f, rpb);
    prep_kernel<<<354, 256, 0, stream>>>(W2, wgcf, wtpf, wt1f, Ws, ctx, Wctx, bt, b1, W1,
                                         wtpp, wt1p, bigp, wsp, cpb1);
    vsn_kernel<<<BT / 64, 512, 0, stream>>>(inp, wtpp, wt1p, bigp, wsp,
                                            b2, bgc, rpb, cpb1, gm, bt2, bs,
                                            out_sel, out_w);
}

// Round 14
// 189.781 us; speedup vs baseline: 1.7231x; 1.0180x over previous
//
#include <hip/hip_runtime.h>

#define NB 64
#define NT 512
#define NVAR 16
#define VDIM 16
#define DD 64
#define FF 256
#define BT (NB*NT)
#define LN_EPS 1e-3f
#define LOG2E 1.4426950408889634f

typedef __attribute__((ext_vector_type(8))) short bf8;   // 8 bf16 = one MFMA A/B operand
typedef __attribute__((ext_vector_type(4))) float f4;
typedef __attribute__((ext_vector_type(4))) int i4;
typedef __attribute__((ext_vector_type(4))) unsigned u4;

// ---- ws layout (bytes) ----
// ALGEBRAIC FOLDS (all exact fp32 at prep):
//   rpb[n]     = bt@Wp + bp                      (res bias, per var)
//   cpb1[b][n] = (ctx@Wctx + bt)@W1 + b1         (h1 bias, per batch-var)
//   wtpf       = Wt@Wp, wt1f = Wt@W1             (K=16 mats off xv)
//   wgcf       = log2e*W2@Wg, bgc = log2e*(b2@Wg+bg)  (gate through W2)
// vsn walls per var: A) K=16 pair off xv  B) K=64 pair off h1.
#define CPB1_OFF   0                  // 64*16*64 f32 = 256KB
#define RPB_OFF    262144             // 16*64 f32 = 4KB
#define WTPP_OFF   266240             // packed Wt@Wp: 16v x 4Mi x 64 x 16B = 64KB
#define WT1P_OFF   331776             // packed Wt@W1: 64KB
#define BIGP_OFF   397312             // 2 mats x 16v x 16 frags x 64 x 16B = 512KB
#define WSP_OFF    921600             // 16 frags x 64 x 16B = 16KB
#define BGC_OFF    937984             // 16*64 f32 = 4KB
#define WGCF_OFF   942080             // wgc float intermediate 256KB
#define WTPF_OFF   1204224            // Wt@Wp float intermediate 64KB
#define WT1F_OFF   1269760            // Wt@W1 float intermediate 64KB
// bigp frag layout per var-mat (16 frags): idx = (c*2+hl)*4 + Mi ; mats 0=W2 1=wgcf

// ---- precise RNE split (prep-time only) ----
__device__ __forceinline__ void split1(float x, unsigned &hb, float &lo) {
    unsigned u = __builtin_bit_cast(unsigned, x);
    unsigned r = u + 0x7fffu + ((u >> 16) & 1u);
    hb = r >> 16;
    lo = x - __builtin_bit_cast(float, r & 0xffff0000u);
}
__device__ __forceinline__ unsigned rnepk(float x, float y) {
    unsigned a = __builtin_bit_cast(unsigned, x);
    unsigned b = __builtin_bit_cast(unsigned, y);
    a = a + 0x7fffu + ((a >> 16) & 1u);
    b = b + 0x7fffu + ((b >> 16) & 1u);
    return (a >> 16) | (b & 0xffff0000u);
}
__device__ __forceinline__ void split4(f4 v, unsigned &h0, unsigned &h1,
                                       unsigned &l0, unsigned &l1) {
    unsigned b0,b1,b2,b3; float q0,q1,q2,q3;
    split1(v.x,b0,q0); split1(v.y,b1,q1); split1(v.z,b2,q2); split1(v.w,b3,q3);
    h0 = b0 | (b1<<16); h1 = b2 | (b3<<16);
    l0 = rnepk(q0,q1); l1 = rnepk(q2,q3);
}
// ---- fast truncation split (hot path): hi = trunc(x), lo = trunc(x - hi) ----
__device__ __forceinline__ void split4f(f4 v, unsigned &h0, unsigned &h1,
                                        unsigned &l0, unsigned &l1) {
    unsigned a0 = __builtin_bit_cast(unsigned, v.x);
    unsigned a1 = __builtin_bit_cast(unsigned, v.y);
    unsigned a2 = __builtin_bit_cast(unsigned, v.z);
    unsigned a3 = __builtin_bit_cast(unsigned, v.w);
    unsigned m0 = a0 & 0xffff0000u, m1 = a1 & 0xffff0000u;
    unsigned m2 = a2 & 0xffff0000u, m3 = a3 & 0xffff0000u;
    h0 = (a0 >> 16) | m1;
    h1 = (a2 >> 16) | m3;
    float lx = v.x - __builtin_bit_cast(float, m0);
    float ly = v.y - __builtin_bit_cast(float, m1);
    float lz = v.z - __builtin_bit_cast(float, m2);
    float lw = v.w - __builtin_bit_cast(float, m3);
    l0 = (__builtin_bit_cast(unsigned, lx) >> 16) |
         (__builtin_bit_cast(unsigned, ly) & 0xffff0000u);
    l1 = (__builtin_bit_cast(unsigned, lz) >> 16) |
         (__builtin_bit_cast(unsigned, lw) & 0xffff0000u);
}
__device__ __forceinline__ bf8 afrag(u4 w) { return __builtin_bit_cast(bf8, w); }
__device__ __forceinline__ bf8 mk_b4(unsigned w0, unsigned w1, unsigned w2, unsigned w3) {
    i4 t; t.x = (int)w0; t.y = (int)w1; t.z = (int)w2; t.w = (int)w3;
    return __builtin_bit_cast(bf8, t);
}
// duplicated-B operands (K=16 stages)
__device__ __forceinline__ bf8 mk_bhh(unsigned h0, unsigned h1) {
    i4 t; t.x = (int)h0; t.y = (int)h1; t.z = (int)h0; t.w = (int)h1;
    return __builtin_bit_cast(bf8, t);
}
__device__ __forceinline__ bf8 mk_bl0(unsigned l0, unsigned l1) {
    i4 t; t.x = (int)l0; t.y = (int)l1; t.z = 0; t.w = 0;
    return __builtin_bit_cast(bf8, t);
}

__device__ __forceinline__ f4 mfma2(f4 acc, bf8 Af, bf8 Bh, bf8 Bl) {
    acc = __builtin_amdgcn_mfma_f32_16x16x32_bf16(Af, Bh, acc, 0,0,0);
    acc = __builtin_amdgcn_mfma_f32_16x16x32_bf16(Af, Bl, acc, 0,0,0);
    return acc;
}

// acc (C-layout) -> B-operand frags of the next stage (pure in-lane repack)
__device__ __forceinline__ void acc_to_frags1(const f4 acc[4],
        unsigned fh[4][2], unsigned fl[4][2]) {
    #pragma unroll
    for (int Ks = 0; Ks < 4; ++Ks)
        split4f(acc[Ks], fh[Ks][0], fh[Ks][1], fl[Ks][0], fl[Ks][1]);
}
// Paired 64x64 GEMM-stage, full-K: both mats consume the SAME B operands.
// 6 MFMAs per Mi per mat; terms Wh.xh + Wl.xh + Wh.xl (Wl.xl ~2^-16 dropped).
// R14 MLP-DEEPENING: all 8 weight loads of an Mi batch (both mats) issue
// BEFORE any MFMA consumes them -> one wait-point per Mi instead of two,
// 8 loads in flight at each wall batch. Transient-only +32 regs (peak ~106
// < 128 cap; distinct from R11's +16 LONG-LIVED which spilled).
// NOTE (R12): do NOT wrap in s_setprio — measured +17% regression.
__device__ __forceinline__ void run_stage6_pair(const u4* __restrict__ ap0,
        const u4* __restrict__ ap1, int lane,
        const unsigned fh[4][2], const unsigned fl[4][2], f4 acc0[4], f4 acc1[4]) {
    const bf8 Bh0 = mk_b4(fh[0][0], fh[0][1], fh[1][0], fh[1][1]);
    const bf8 Bh1 = mk_b4(fh[2][0], fh[2][1], fh[3][0], fh[3][1]);
    const bf8 Bl0 = mk_b4(fl[0][0], fl[0][1], fl[1][0], fl[1][1]);
    const bf8 Bl1 = mk_b4(fl[2][0], fl[2][1], fl[3][0], fl[3][1]);
    #pragma unroll
    for (int Mi = 0; Mi < 4; ++Mi) {
        // ---- issue all 8 loads of this Mi batch up front (max MLP) ----
        const u4 a00 = ap0[(     Mi)*64 + lane];
        const u4 a01 = ap0[( 4 + Mi)*64 + lane];
        const u4 a02 = ap0[( 8 + Mi)*64 + lane];
        const u4 a03 = ap0[(12 + Mi)*64 + lane];
        const u4 a10 = ap1[(     Mi)*64 + lane];
        const u4 a11 = ap1[( 4 + Mi)*64 + lane];
        const u4 a12 = ap1[( 8 + Mi)*64 + lane];
        const u4 a13 = ap1[(12 + Mi)*64 + lane];
        f4 a = acc0[Mi];
        a = __builtin_amdgcn_mfma_f32_16x16x32_bf16(afrag(a00), Bh0, a, 0,0,0);
        a = __builtin_amdgcn_mfma_f32_16x16x32_bf16(afrag(a02), Bh1, a, 0,0,0);
        a = __builtin_amdgcn_mfma_f32_16x16x32_bf16(afrag(a01), Bh0, a, 0,0,0);
        a = __builtin_amdgcn_mfma_f32_16x16x32_bf16(afrag(a03), Bh1, a, 0,0,0);
        a = __builtin_amdgcn_mfma_f32_16x16x32_bf16(afrag(a00), Bl0, a, 0,0,0);
        a = __builtin_amdgcn_mfma_f32_16x16x32_bf16(afrag(a02), Bl1, a, 0,0,0);
        acc0[Mi] = a;
        f4 g = acc1[Mi];
        g = __builtin_amdgcn_mfma_f32_16x16x32_bf16(afrag(a10), Bh0, g, 0,0,0);
        g = __builtin_amdgcn_mfma_f32_16x16x32_bf16(afrag(a12), Bh1, g, 0,0,0);
        g = __builtin_amdgcn_mfma_f32_16x16x32_bf16(afrag(a11), Bh0, g, 0,0,0);
        g = __builtin_amdgcn_mfma_f32_16x16x32_bf16(afrag(a13), Bh1, g, 0,0,0);
        g = __builtin_amdgcn_mfma_f32_16x16x32_bf16(afrag(a10), Bl0, g, 0,0,0);
        g = __builtin_amdgcn_mfma_f32_16x16x32_bf16(afrag(a12), Bl1, g, 0,0,0);
        acc1[Mi] = g;
    }
}

// prep0: all fp32 folds.
// blocks 0..63:  var=bid>>2, quarter: wgcf = log2e*W2@Wg (+ bgc on quarter 0)
// blocks 64..79: var=bid-64: wtpf = Wt@Wp, wt1f = Wt@W1, rpb = bt@Wp + bp
__global__ void prep0_kernel(const float* __restrict__ Wt, const float* __restrict__ W1,
                             const float* __restrict__ W2, const float* __restrict__ Wg,
                             const float* __restrict__ Wp,
                             const float* __restrict__ b2, const float* __restrict__ bg,
                             const float* __restrict__ bt, const float* __restrict__ bp,
                             float* __restrict__ wgcf, float* __restrict__ bgc,
                             float* __restrict__ wtpf, float* __restrict__ wt1f,
                             float* __restrict__ rpb) {
    __shared__ float sh[9216];
    const int tid = threadIdx.x;
    if (blockIdx.x < 64) {
        const int var = blockIdx.x >> 2;
        const int kb  = (blockIdx.x & 3) * 16;
        const float* wgsrc = Wg + var * 4096;
        #pragma unroll
        for (int i = 0; i < 16; ++i) sh[i*256 + tid] = wgsrc[i*256 + tid];
        __syncthreads();
        const int m  = tid & 63;
        const int ks = tid >> 6;            // 0..3
        const float* w2 = W2 + var * 4096;
        #pragma unroll
        for (int kk = 0; kk < 4; ++kk) {
            const int k = kb + ks * 4 + kk;
            float acc = 0.f;
            #pragma unroll 8
            for (int e = 0; e < 64; ++e) acc += w2[k*64 + e] * sh[e*64 + m];
            wgcf[(size_t)var*4096 + k*64 + m] = LOG2E * acc;
        }
        if ((blockIdx.x & 3) == 0 && tid < 64) {
            float acc = bg[var*64 + m];
            #pragma unroll 8
            for (int e = 0; e < 64; ++e) acc += b2[var*64 + e] * sh[e*64 + m];
            bgc[var*64 + m] = LOG2E * acc;
        }
        return;
    }
    const int var = blockIdx.x - 64;
    // sh: [0..4095] = Wp[var], [4096..8191] = W1[var], [8192..9215] = Wt[var]
    const float* wpsrc = Wp + var * 4096;
    const float* w1src = W1 + var * 4096;
    const float* wtsrc = Wt + var * 1024;
    #pragma unroll
    for (int i = 0; i < 16; ++i) sh[i*256 + tid]        = wpsrc[i*256 + tid];
    #pragma unroll
    for (int i = 0; i < 16; ++i) sh[4096 + i*256 + tid] = w1src[i*256 + tid];
    #pragma unroll
    for (int i = 0; i < 4; ++i)  sh[8192 + i*256 + tid] = wtsrc[i*256 + tid];
    __syncthreads();
    const int m  = tid & 63;
    const int vq = tid >> 6;                // 0..3
    #pragma unroll
    for (int vv = 0; vv < 4; ++vv) {
        const int v = vq*4 + vv;
        float ap = 0.f, a1 = 0.f;
        #pragma unroll 8
        for (int d = 0; d < 64; ++d) {
            const float w = sh[8192 + v*64 + d];
            ap += w * sh[d*64 + m];
            a1 += w * sh[4096 + d*64 + m];
        }
        wtpf[(size_t)var*1024 + v*64 + m] = ap;
        wt1f[(size_t)var*1024 + v*64 + m] = a1;
    }
    if (tid < 64) {
        float acc = bp[var*64 + tid];
        #pragma unroll 8
        for (int d = 0; d < 64; ++d) acc += bt[var*64 + d] * sh[d*64 + tid];
        rpb[var*64 + tid] = acc;
    }
}

// prep: pack (blocks 0..97) + context cpb1 (blocks 98..353).
__global__ void prep_kernel(const float* __restrict__ W2, const float* __restrict__ wgcf,
                            const float* __restrict__ wtpf, const float* __restrict__ wt1f,
                            const float* __restrict__ Ws,
                            const float* __restrict__ ctx, const float* __restrict__ Wctx,
                            const float* __restrict__ bt, const float* __restrict__ b1,
                            const float* __restrict__ W1,
                            u4* __restrict__ wtpp, u4* __restrict__ wt1p,
                            u4* __restrict__ bigp, u4* __restrict__ wsp,
                            float* __restrict__ cpb1) {
    if (blockIdx.x >= 98) {
        // cpb1[b][n][d] = (ctx@Wctx + bt)@W1 + b1  (fp32)
        __shared__ float cp[4][64];
        const int sub = threadIdx.x >> 6, d = threadIdx.x & 63;
        const int bn = (blockIdx.x - 98) * 4 + sub;
        const int b = bn >> 4, n = bn & 15;
        const float* __restrict__ wc = Wctx + n * DD * DD;
        const float* __restrict__ c  = ctx + b * DD;
        float acc = bt[n * DD + d];
        #pragma unroll 8
        for (int k = 0; k < DD; ++k) acc += c[k] * wc[k * DD + d];
        cp[sub][d] = acc;                   // cprojb row
        __syncthreads();
        const float* __restrict__ w1 = W1 + n * DD * DD;
        float r = b1[n * DD + d];
        #pragma unroll 8
        for (int k = 0; k < DD; ++k) r += cp[sub][k] * w1[k * DD + d];
        cpb1[bn * DD + d] = r;
        return;
    }
    const int t = blockIdx.x * 256 + threadIdx.x;
    if (t < 16384) {
        // bigp: mats 0=W2, 1=wgcf; per thread one (var,mat,c,Mi) h+l frag
        const int lane = t & 63, Mi = (t>>6)&3, c = (t>>8)&1, mat = (t>>9)&1, var = t>>10;
        const float* src = ((mat==0) ? W2 : wgcf) + (size_t)var*4096;
        const int m = 16*Mi + (lane&15), q = lane>>4;
        const int k0 = 32*c + 4*q;
        unsigned hb[8]; float lo[8];
        #pragma unroll
        for (int j = 0; j < 4; ++j) split1(src[(k0+j)*64+m],    hb[j],   lo[j]);
        #pragma unroll
        for (int j = 0; j < 4; ++j) split1(src[(k0+16+j)*64+m], hb[4+j], lo[4+j]);
        u4 hf, lf;
        hf.x = hb[0]|(hb[1]<<16); hf.y = hb[2]|(hb[3]<<16);
        hf.z = hb[4]|(hb[5]<<16); hf.w = hb[6]|(hb[7]<<16);
        lf.x = rnepk(lo[0],lo[1]); lf.y = rnepk(lo[2],lo[3]);
        lf.z = rnepk(lo[4],lo[5]); lf.w = rnepk(lo[6],lo[7]);
        u4* base = bigp + (size_t)((var*2+mat)*16)*64;
        base[((c*2+0)*4 + Mi)*64 + lane] = hf;
        base[((c*2+1)*4 + Mi)*64 + lane] = lf;
    } else if (t < 24576) {
        // wtpp / wt1p: K=16 [Wh|Wl] frags from wtpf / wt1f
        const int r = t - 16384;            // 0..8191
        const int which = r >> 12;          // 0: wtpf, 1: wt1f
        const int rr = r & 4095;
        const int lane = rr & 63, Mi = (rr>>6)&3, var = rr>>8;
        const int m = 16*Mi + (lane&15), k0 = 4*(lane>>4);
        const float* src = (which ? wt1f : wtpf) + (size_t)var*1024;
        f4 v;
        v.x = src[(k0+0)*64+m]; v.y = src[(k0+1)*64+m];
        v.z = src[(k0+2)*64+m]; v.w = src[(k0+3)*64+m];
        unsigned h0,h1,l0,l1; split4(v,h0,h1,l0,l1);
        u4 o; o.x=h0; o.y=h1; o.z=l0; o.w=l1;
        (which ? wt1p : wtpp)[(var*4+Mi)*64 + lane] = o;
    } else if (t < 25088) {
        // Ws: full-K chunks (c=0..7), h-frag + l-frag per thread
        const int r = t - 24576;
        const int lane = r & 63, c = r >> 6;
        const int n = lane & 15, q = lane >> 4;
        const int k0 = 32*c + 4*q;
        unsigned hb[8]; float lo[8];
        #pragma unroll
        for (int j = 0; j < 4; ++j) split1(Ws[(k0+j)*16+n],    hb[j],   lo[j]);
        #pragma unroll
        for (int j = 0; j < 4; ++j) split1(Ws[(k0+16+j)*16+n], hb[4+j], lo[4+j]);
        u4 hf, lf;
        hf.x = hb[0]|(hb[1]<<16); hf.y = hb[2]|(hb[3]<<16);
        hf.z = hb[4]|(hb[5]<<16); hf.w = hb[6]|(hb[7]<<16);
        lf.x = rnepk(lo[0],lo[1]); lf.y = rnepk(lo[2],lo[3]);
        lf.z = rnepk(lo[4],lo[5]); lf.w = rnepk(lo[6],lo[7]);
        wsp[(c*2+0)*64 + lane] = hf;
        wsp[(c*2+1)*64 + lane] = lf;
    }
}

// Main: block = 512 threads = 8 waves, 64 tokens; grid = 512 (R0 skeleton).
// SESSION LEDGER (all measured):
//   R10 sumsq-LN        -> absmax 4x FAIL (cancellation; LN must be two-pass)
//   R11 pair-fusion@128  -> +16 held regs spill 453MB (R9 body fits EXACTLY)
//   R12 s_setprio(MFMA)  -> +17% (load-wave starvation + 53MB scratch)
//   R13 = R9 reproduced: vsn 91.0us, absmax 0.0039 (verified optimum)
// REGISTER-CAP LEDGER: cap 128 + sel-in-LDS fits; +16 LONG-LIVED regs spills;
// cap<128 catastrophic. TRANSIENT regs within a wall batch are the one
// unexplored axis -> THIS ROUND: 8-deep load batches at walls A and B
// (one wait-point per Mi instead of two; transient peak ~106 < 128).
#define PSEL_OFF 0          // 128 rows x 68 dw = 8704 dw
#define WSEL_OFF 8704       // 4 tq x 16 n x 17 = 1088 dw
#define SMEM_DW  9792       // 39168 B; 2 blocks/CU = 78KB <= 160KB

__global__ __launch_bounds__(512, 4)
void vsn_kernel(const float* __restrict__ inp,
                const u4* __restrict__ wtpp, const u4* __restrict__ wt1p,
                const u4* __restrict__ bigp, const u4* __restrict__ wsp,
                const float* __restrict__ b2, const float* __restrict__ bgc,
                const float* __restrict__ rpb, const float* __restrict__ cpb1,
                const float* __restrict__ gamma_, const float* __restrict__ beta_,
                const float* __restrict__ bs,
                float* __restrict__ out_sel, float* __restrict__ out_w) {
    __shared__ float smem[SMEM_DW];

    const int tid  = threadIdx.x;
    const int lane = tid & 63;
    const int wv   = tid >> 6;
    const int grp  = wv & 1;                    // var group (8 vars)
    const int tq   = wv >> 1;                   // token quarter (16 tokens)
    const int qd   = lane >> 4;
    const int l15  = lane & 15;
    const int tile0 = blockIdx.x * 64;
    const int b     = blockIdx.x >> 3;          // tile0 / NT
    const int tok0  = tile0 + tq * 16;

    const float* row = inp + (size_t)(tok0 + l15) * FF;   // my token's feature row

    // ---------------- logits via MFMA + softmax (per wave, 16 tokens) -------
    {
        f4 lacc = *(const f4*)(bs + 4*qd);      // n = 4*qd + reg
        #pragma unroll 4
        for (int c = 0; c < 8; ++c) {
            const u4 wh = wsp[(c*2+0)*64 + lane];
            const u4 wl = wsp[(c*2+1)*64 + lane];
            const f4 v1 = *(const f4*)(row + 32*c + 4*qd);
            const f4 v2 = *(const f4*)(row + 32*c + 16 + 4*qd);
            unsigned h0,h1,l0,l1,h2,h3,l2,l3;
            split4f(v1,h0,h1,l0,l1);
            split4f(v2,h2,h3,l2,l3);
            const bf8 Bh = mk_b4(h0,h1,h2,h3);
            const bf8 Bl = mk_b4(l0,l1,l2,l3);
            lacc = __builtin_amdgcn_mfma_f32_16x16x32_bf16(afrag(wh), Bh, lacc, 0,0,0);
            lacc = __builtin_amdgcn_mfma_f32_16x16x32_bf16(afrag(wl), Bh, lacc, 0,0,0);
            lacc = __builtin_amdgcn_mfma_f32_16x16x32_bf16(afrag(wh), Bl, lacc, 0,0,0);
        }
        float mx = fmaxf(fmaxf(lacc.x,lacc.y), fmaxf(lacc.z,lacc.w));
        mx = fmaxf(mx, __shfl_xor(mx, 16));
        mx = fmaxf(mx, __shfl_xor(mx, 32));
        float e0 = __expf(lacc.x-mx), e1 = __expf(lacc.y-mx);
        float e2 = __expf(lacc.z-mx), e3 = __expf(lacc.w-mx);
        float s = e0+e1+e2+e3;
        s += __shfl_xor(s, 16);
        s += __shfl_xor(s, 32);
        const float rs = __builtin_amdgcn_rcpf(s);
        e0 *= rs; e1 *= rs; e2 *= rs; e3 *= rs;
        const int base = WSEL_OFF + tq*272 + (4*qd)*17 + l15;
        smem[base + 0*17] = e0;
        smem[base + 1*17] = e1;
        smem[base + 2*17] = e2;
        smem[base + 3*17] = e3;
        if (grp == 0) {
            f4 o; o.x=e0; o.y=e1; o.z=e2; o.w=e3;
            *(f4*)(out_w + (size_t)(tok0 + l15)*16 + 4*qd) = o;
        }
    }

    // ---------------- per-variable GRN chain (8 vars per wave) --------------
    const int sbase = PSEL_OFF + (grp*64 + tq*16 + l15)*68 + 4*qd;

    #pragma unroll 1
    for (int vi = 0; vi < 8; ++vi) {
        const int n = grp*8 + vi;
        unsigned fh[4][2], fl[4][2];

        // wall A (K=16 pair off xv): res = wtpf^T xv + rpb ; h1pre = wt1f^T xv + cpb1
        // 8-deep load batch: all weight loads issue before the MFMA cluster.
        f4 racc[4], hacc[4];
        #pragma unroll
        for (int Mi = 0; Mi < 4; ++Mi) {
            racc[Mi] = *(const f4*)(rpb  + n*DD + 16*Mi + 4*qd);
            hacc[Mi] = *(const f4*)(cpb1 + (size_t)(b*NVAR+n)*DD + 16*Mi + 4*qd);
        }
        {
            const f4 v = *(const f4*)(row + n*16 + 4*qd);
            u4 wA[4], wB[4];
            #pragma unroll
            for (int Mi = 0; Mi < 4; ++Mi) {
                wA[Mi] = wtpp[(n*4+Mi)*64 + lane];
                wB[Mi] = wt1p[(n*4+Mi)*64 + lane];
            }
            unsigned xh0,xh1,xl0,xl1;
            split4f(v, xh0, xh1, xl0, xl1);
            const bf8 Bh = mk_bhh(xh0, xh1);
            const bf8 Bl = mk_bl0(xl0, xl1);
            #pragma unroll
            for (int Mi = 0; Mi < 4; ++Mi) {
                racc[Mi] = mfma2(racc[Mi], afrag(wA[Mi]), Bh, Bl);
                hacc[Mi] = mfma2(hacc[Mi], afrag(wB[Mi]), Bh, Bl);
            }
        }
        #pragma unroll
        for (int Mi = 0; Mi < 4; ++Mi) {
            f4& v = hacc[Mi];
            v.x = v.x > 0.f ? v.x : (__expf(v.x)-1.f);
            v.y = v.y > 0.f ? v.y : (__expf(v.y)-1.f);
            v.z = v.z > 0.f ? v.z : (__expf(v.z)-1.f);
            v.w = v.w > 0.f ? v.w : (__expf(v.w)-1.f);
        }
        acc_to_frags1(hacc, fh, fl);   // h1 frags

        // wall B: h2 = W2^T h1 + b2 ; g' = wgcf^T h1 + bgc  (shared h1-frags)
        f4 gacc[4];
        #pragma unroll
        for (int Mi = 0; Mi < 4; ++Mi) {
            hacc[Mi] = *(const f4*)(b2  + n*DD + 16*Mi + 4*qd);
            gacc[Mi] = *(const f4*)(bgc + n*DD + 16*Mi + 4*qd);
        }
        run_stage6_pair(bigp + (size_t)(n*2 + 0)*1024,
                        bigp + (size_t)(n*2 + 1)*1024, lane, fh, fl, hacc, gacc);

        // z = h2 * rcp(1 + exp2(-g')) + res
        f4 z[4];
        #pragma unroll
        for (int Mi = 0; Mi < 4; ++Mi) {
            const f4 gv = gacc[Mi];
            z[Mi].x = hacc[Mi].x * __builtin_amdgcn_rcpf(1.f + __builtin_amdgcn_exp2f(-gv.x)) + racc[Mi].x;
            z[Mi].y = hacc[Mi].y * __builtin_amdgcn_rcpf(1.f + __builtin_amdgcn_exp2f(-gv.y)) + racc[Mi].y;
            z[Mi].z = hacc[Mi].z * __builtin_amdgcn_rcpf(1.f + __builtin_amdgcn_exp2f(-gv.z)) + racc[Mi].z;
            z[Mi].w = hacc[Mi].w * __builtin_amdgcn_rcpf(1.f + __builtin_amdgcn_exp2f(-gv.w)) + racc[Mi].w;
        }
        // TWO-PASS LayerNorm (R10 lesson: sumsq form cancels — keep two-pass)
        float s = 0.f;
        #pragma unroll
        for (int Mi = 0; Mi < 4; ++Mi) s += z[Mi].x + z[Mi].y + z[Mi].z + z[Mi].w;
        s += __shfl_xor(s, 16);
        s += __shfl_xor(s, 32);
        const float mu = s * (1.f/64.f);
        float q = 0.f;
        #pragma unroll
        for (int Mi = 0; Mi < 4; ++Mi) {
            float dx = z[Mi].x - mu; q += dx*dx;
            dx = z[Mi].y - mu; q += dx*dx;
            dx = z[Mi].z - mu; q += dx*dx;
            dx = z[Mi].w - mu; q += dx*dx;
        }
        q += __shfl_xor(q, 16);
        q += __shfl_xor(q, 32);
        const float rstd = rsqrtf(q*(1.f/64.f) + LN_EPS);

        const float wn = smem[WSEL_OFF + tq*272 + n*17 + l15];
        #pragma unroll
        for (int Mi = 0; Mi < 4; ++Mi) {
            const f4 gm = *(const f4*)(gamma_ + n*DD + 16*Mi + 4*qd);
            const f4 bb = *(const f4*)(beta_  + n*DD + 16*Mi + 4*qd);
            f4 cb;
            cb.x = wn*((z[Mi].x-mu)*rstd*gm.x + bb.x);
            cb.y = wn*((z[Mi].y-mu)*rstd*gm.y + bb.y);
            cb.z = wn*((z[Mi].z-mu)*rstd*gm.z + bb.z);
            cb.w = wn*((z[Mi].w-mu)*rstd*gm.w + bb.w);
            if (vi == 0) {
                *(f4*)&smem[sbase + 16*Mi] = cb;
            } else {
                const f4 o = *(f4*)&smem[sbase + 16*Mi];
                *(f4*)&smem[sbase + 16*Mi] = o + cb;
            }
        }
    }

    __syncthreads();
    {
        const int tokloc = tid >> 3;            // 0..63
        const int d0 = (tid & 7) * 8;
        const int rbase = PSEL_OFF + tokloc*68 + d0;
        const f4 a0 = *(f4*)&smem[rbase];
        const f4 a1 = *(f4*)&smem[rbase + 4];
        const f4 b0 = *(f4*)&smem[rbase + 64*68];
        const f4 b1v = *(f4*)&smem[rbase + 64*68 + 4];
        float* po = out_sel + (size_t)(tile0+tokloc)*DD + d0;
        *(f4*)po     = a0 + b0;
        *(f4*)(po+4) = a1 + b1v;
    }
}

extern "C" void kernel_launch(void* const* d_in, const int* in_sizes, int n_in,
                              void* d_out, int out_size, void* d_ws, size_t ws_size,
                              hipStream_t stream) {
    const float* inp  = (const float*)d_in[0];
    const float* ctx  = (const float*)d_in[1];
    const float* Wt   = (const float*)d_in[2];
    const float* bt   = (const float*)d_in[3];
    const float* Wctx = (const float*)d_in[4];
    const float* W1   = (const float*)d_in[5];
    const float* b1   = (const float*)d_in[6];
    const float* W2   = (const float*)d_in[7];
    const float* b2   = (const float*)d_in[8];
    const float* Wg   = (const float*)d_in[9];
    const float* bg   = (const float*)d_in[10];
    const float* Wp   = (const float*)d_in[11];
    const float* bp   = (const float*)d_in[12];
    const float* gm   = (const float*)d_in[13];
    const float* bt2  = (const float*)d_in[14];
    const float* Ws   = (const float*)d_in[15];
    const float* bs   = (const float*)d_in[16];

    float* out_sel = (float*)d_out;
    float* out_w   = out_sel + (size_t)BT * DD;

    char* ws = (char*)d_ws;
    float* cpb1 = (float*)(ws + CPB1_OFF);
    float* rpb  = (float*)(ws + RPB_OFF);
    u4* wtpp = (u4*)(ws + WTPP_OFF);
    u4* wt1p = (u4*)(ws + WT1P_OFF);
    u4* bigp = (u4*)(ws + BIGP_OFF);
    u4* wsp  = (u4*)(ws + WSP_OFF);
    float* bgc  = (float*)(ws + BGC_OFF);
    float* wgcf = (float*)(ws + WGCF_OFF);
    float* wtpf = (float*)(ws + WTPF_OFF);
    float* wt1f = (float*)(ws + WT1F_OFF);

    prep0_kernel<<<80, 256, 0, stream>>>(Wt, W1, W2, Wg, Wp, b2, bg, bt, bp,
                                         wgcf, bgc, wtpf, wt1f, rpb);
    prep_kernel<<<354, 256, 0, stream>>>(W2, wgcf, wtpf, wt1f, Ws, ctx, Wctx, bt, b1, W1,
                                         wtpp, wt1p, bigp, wsp, cpb1);
    vsn_kernel<<<BT / 64, 512, 0, stream>>>(inp, wtpp, wt1p, bigp, wsp,
                                            b2, bgc, rpb, cpb1, gm, bt2, bs,
                                            out_sel, out_w);
}

// Round 15
// 186.217 us; speedup vs baseline: 1.7561x; 1.0191x over previous
//
#include <hip/hip_runtime.h>

#define NB 64
#define NT 512
#define NVAR 16
#define VDIM 16
#define DD 64
#define FF 256
#define BT (NB*NT)
#define LN_EPS 1e-3f
#define LOG2E 1.4426950408889634f

typedef __attribute__((ext_vector_type(8))) short bf8;   // 8 bf16 = one MFMA A/B operand
typedef __attribute__((ext_vector_type(4))) float f4;
typedef __attribute__((ext_vector_type(4))) int i4;
typedef __attribute__((ext_vector_type(4))) unsigned u4;

// ---- ws layout (bytes) ----
// ALGEBRAIC FOLDS (all exact fp32, computed in-block at pack time — R15 merged
// the former prep0 into prep: folds never touch memory as f32):
//   rpb[n]     = bt@Wp + bp                      (res bias, per var)
//   cpb1[b][n] = (ctx@Wctx + bt)@W1 + b1         (h1 bias, per batch-var)
//   wtpp/wt1p  = packed Wt@Wp, Wt@W1             (K=16 mats off xv)
//   bigp mat1  = packed log2e*W2@Wg; bgc = log2e*(b2@Wg+bg)  (gate through W2)
// vsn walls per var: A) K=16 pair off xv  B) K=64 pair off h1.
#define CPB1_OFF   0                  // 64*16*64 f32 = 256KB
#define RPB_OFF    262144             // 16*64 f32 = 4KB
#define WTPP_OFF   266240             // packed Wt@Wp: 16v x 4Mi x 64 x 16B = 64KB
#define WT1P_OFF   331776             // packed Wt@W1: 64KB
#define BIGP_OFF   397312             // 2 mats x 16v x 16 frags x 64 x 16B = 512KB
#define WSP_OFF    921600             // 16 frags x 64 x 16B = 16KB
#define BGC_OFF    937984             // 16*64 f32 = 4KB
// bigp frag layout per var-mat (16 frags): idx = (c*2+hl)*4 + Mi ; mats 0=W2 1=wgcf

// ---- precise RNE split (prep-time only) ----
__device__ __forceinline__ void split1(float x, unsigned &hb, float &lo) {
    unsigned u = __builtin_bit_cast(unsigned, x);
    unsigned r = u + 0x7fffu + ((u >> 16) & 1u);
    hb = r >> 16;
    lo = x - __builtin_bit_cast(float, r & 0xffff0000u);
}
__device__ __forceinline__ unsigned rnepk(float x, float y) {
    unsigned a = __builtin_bit_cast(unsigned, x);
    unsigned b = __builtin_bit_cast(unsigned, y);
    a = a + 0x7fffu + ((a >> 16) & 1u);
    b = b + 0x7fffu + ((b >> 16) & 1u);
    return (a >> 16) | (b & 0xffff0000u);
}
__device__ __forceinline__ void split4(f4 v, unsigned &h0, unsigned &h1,
                                       unsigned &l0, unsigned &l1) {
    unsigned b0,b1,b2,b3; float q0,q1,q2,q3;
    split1(v.x,b0,q0); split1(v.y,b1,q1); split1(v.z,b2,q2); split1(v.w,b3,q3);
    h0 = b0 | (b1<<16); h1 = b2 | (b3<<16);
    l0 = rnepk(q0,q1); l1 = rnepk(q2,q3);
}
// ---- fast truncation split (hot path): hi = trunc(x), lo = trunc(x - hi) ----
__device__ __forceinline__ void split4f(f4 v, unsigned &h0, unsigned &h1,
                                        unsigned &l0, unsigned &l1) {
    unsigned a0 = __builtin_bit_cast(unsigned, v.x);
    unsigned a1 = __builtin_bit_cast(unsigned, v.y);
    unsigned a2 = __builtin_bit_cast(unsigned, v.z);
    unsigned a3 = __builtin_bit_cast(unsigned, v.w);
    unsigned m0 = a0 & 0xffff0000u, m1 = a1 & 0xffff0000u;
    unsigned m2 = a2 & 0xffff0000u, m3 = a3 & 0xffff0000u;
    h0 = (a0 >> 16) | m1;
    h1 = (a2 >> 16) | m3;
    float lx = v.x - __builtin_bit_cast(float, m0);
    float ly = v.y - __builtin_bit_cast(float, m1);
    float lz = v.z - __builtin_bit_cast(float, m2);
    float lw = v.w - __builtin_bit_cast(float, m3);
    l0 = (__builtin_bit_cast(unsigned, lx) >> 16) |
         (__builtin_bit_cast(unsigned, ly) & 0xffff0000u);
    l1 = (__builtin_bit_cast(unsigned, lz) >> 16) |
         (__builtin_bit_cast(unsigned, lw) & 0xffff0000u);
}
__device__ __forceinline__ bf8 afrag(u4 w) { return __builtin_bit_cast(bf8, w); }
__device__ __forceinline__ bf8 mk_b4(unsigned w0, unsigned w1, unsigned w2, unsigned w3) {
    i4 t; t.x = (int)w0; t.y = (int)w1; t.z = (int)w2; t.w = (int)w3;
    return __builtin_bit_cast(bf8, t);
}
// duplicated-B operands (K=16 stages)
__device__ __forceinline__ bf8 mk_bhh(unsigned h0, unsigned h1) {
    i4 t; t.x = (int)h0; t.y = (int)h1; t.z = (int)h0; t.w = (int)h1;
    return __builtin_bit_cast(bf8, t);
}
__device__ __forceinline__ bf8 mk_bl0(unsigned l0, unsigned l1) {
    i4 t; t.x = (int)l0; t.y = (int)l1; t.z = 0; t.w = 0;
    return __builtin_bit_cast(bf8, t);
}

__device__ __forceinline__ f4 mfma2(f4 acc, bf8 Af, bf8 Bh, bf8 Bl) {
    acc = __builtin_amdgcn_mfma_f32_16x16x32_bf16(Af, Bh, acc, 0,0,0);
    acc = __builtin_amdgcn_mfma_f32_16x16x32_bf16(Af, Bl, acc, 0,0,0);
    return acc;
}

// acc (C-layout) -> B-operand frags of the next stage (pure in-lane repack)
__device__ __forceinline__ void acc_to_frags1(const f4 acc[4],
        unsigned fh[4][2], unsigned fl[4][2]) {
    #pragma unroll
    for (int Ks = 0; Ks < 4; ++Ks)
        split4f(acc[Ks], fh[Ks][0], fh[Ks][1], fl[Ks][0], fl[Ks][1]);
}
// Paired 64x64 GEMM-stage, full-K: both mats consume the SAME B operands.
// 6 MFMAs per Mi per mat; terms Wh.xh + Wl.xh + Wh.xl (Wl.xl ~2^-16 dropped).
// 8-deep load batches (R14: compiler was already hoisting — kept, it's neutral).
// NOTE (R12): do NOT wrap in s_setprio — measured +17% regression.
__device__ __forceinline__ void run_stage6_pair(const u4* __restrict__ ap0,
        const u4* __restrict__ ap1, int lane,
        const unsigned fh[4][2], const unsigned fl[4][2], f4 acc0[4], f4 acc1[4]) {
    const bf8 Bh0 = mk_b4(fh[0][0], fh[0][1], fh[1][0], fh[1][1]);
    const bf8 Bh1 = mk_b4(fh[2][0], fh[2][1], fh[3][0], fh[3][1]);
    const bf8 Bl0 = mk_b4(fl[0][0], fl[0][1], fl[1][0], fl[1][1]);
    const bf8 Bl1 = mk_b4(fl[2][0], fl[2][1], fl[3][0], fl[3][1]);
    #pragma unroll
    for (int Mi = 0; Mi < 4; ++Mi) {
        const u4 a00 = ap0[(     Mi)*64 + lane];
        const u4 a01 = ap0[( 4 + Mi)*64 + lane];
        const u4 a02 = ap0[( 8 + Mi)*64 + lane];
        const u4 a03 = ap0[(12 + Mi)*64 + lane];
        const u4 a10 = ap1[(     Mi)*64 + lane];
        const u4 a11 = ap1[( 4 + Mi)*64 + lane];
        const u4 a12 = ap1[( 8 + Mi)*64 + lane];
        const u4 a13 = ap1[(12 + Mi)*64 + lane];
        f4 a = acc0[Mi];
        a = __builtin_amdgcn_mfma_f32_16x16x32_bf16(afrag(a00), Bh0, a, 0,0,0);
        a = __builtin_amdgcn_mfma_f32_16x16x32_bf16(afrag(a02), Bh1, a, 0,0,0);
        a = __builtin_amdgcn_mfma_f32_16x16x32_bf16(afrag(a01), Bh0, a, 0,0,0);
        a = __builtin_amdgcn_mfma_f32_16x16x32_bf16(afrag(a03), Bh1, a, 0,0,0);
        a = __builtin_amdgcn_mfma_f32_16x16x32_bf16(afrag(a00), Bl0, a, 0,0,0);
        a = __builtin_amdgcn_mfma_f32_16x16x32_bf16(afrag(a02), Bl1, a, 0,0,0);
        acc0[Mi] = a;
        f4 g = acc1[Mi];
        g = __builtin_amdgcn_mfma_f32_16x16x32_bf16(afrag(a10), Bh0, g, 0,0,0);
        g = __builtin_amdgcn_mfma_f32_16x16x32_bf16(afrag(a12), Bh1, g, 0,0,0);
        g = __builtin_amdgcn_mfma_f32_16x16x32_bf16(afrag(a11), Bh0, g, 0,0,0);
        g = __builtin_amdgcn_mfma_f32_16x16x32_bf16(afrag(a13), Bh1, g, 0,0,0);
        g = __builtin_amdgcn_mfma_f32_16x16x32_bf16(afrag(a10), Bl0, g, 0,0,0);
        g = __builtin_amdgcn_mfma_f32_16x16x32_bf16(afrag(a12), Bl1, g, 0,0,0);
        acc1[Mi] = g;
    }
}

// MERGED prep (R15): one launch, 306 blocks. Folds computed in-block from
// LDS-staged operands — identical fp32 dot order as the old prep0, so the
// packed bits are bitwise identical (register value == stored-then-loaded f32).
//   blocks 0..31   (var,c): stage Wg + W2-rows; pack W2 frags (mat0) and
//                  wgcf = log2e*W2@Wg frags (mat1); bgc on c==0.
//   blocks 32..47  (var): stage Wp,W1,Wt; compute Wt@Wp / Wt@W1 dots and pack
//                  wtpp/wt1p; rpb = bt@Wp + bp.
//   blocks 48..303 cpb1[b][n] = (ctx@Wctx + bt)@W1 + b1   (4 rows/block)
//   blocks 304..305 wsp pack (Ws full-K chunks)
__global__ void prep_kernel(const float* __restrict__ Wt, const float* __restrict__ W1,
                            const float* __restrict__ W2, const float* __restrict__ Wg,
                            const float* __restrict__ Wp, const float* __restrict__ Ws,
                            const float* __restrict__ ctx, const float* __restrict__ Wctx,
                            const float* __restrict__ bt, const float* __restrict__ b1,
                            const float* __restrict__ b2, const float* __restrict__ bg,
                            const float* __restrict__ bp,
                            u4* __restrict__ wtpp, u4* __restrict__ wt1p,
                            u4* __restrict__ bigp, u4* __restrict__ wsp,
                            float* __restrict__ cpb1, float* __restrict__ rpb,
                            float* __restrict__ bgc) {
    __shared__ float sh[9216];
    const int tid = threadIdx.x;
    const int bid = blockIdx.x;
    if (bid < 32) {
        // ---- type A: (var, c) — W2 frags + wgcf frags + bgc ----
        const int var = bid >> 1, c = bid & 1;
        const float* wgsrc = Wg + var*4096;
        const float* w2src = W2 + var*4096 + c*32*64;    // rows [32c, 32c+32)
        #pragma unroll
        for (int i = 0; i < 16; ++i) sh[i*256 + tid] = wgsrc[i*256 + tid];
        #pragma unroll
        for (int i = 0; i < 8; ++i)  sh[4096 + i*256 + tid] = w2src[i*256 + tid];
        __syncthreads();
        const int lane = tid & 63, Mi = tid >> 6;
        const int m = 16*Mi + (lane & 15), q = lane >> 4;
        const int k0 = 4*q;                               // local row in window
        {   // mat 0: W2 frags (straight split of staged rows)
            unsigned hb[8]; float lo[8];
            #pragma unroll
            for (int j = 0; j < 4; ++j) split1(sh[4096 + (k0+j)*64 + m],    hb[j],   lo[j]);
            #pragma unroll
            for (int j = 0; j < 4; ++j) split1(sh[4096 + (k0+16+j)*64 + m], hb[4+j], lo[4+j]);
            u4 hf, lf;
            hf.x = hb[0]|(hb[1]<<16); hf.y = hb[2]|(hb[3]<<16);
            hf.z = hb[4]|(hb[5]<<16); hf.w = hb[6]|(hb[7]<<16);
            lf.x = rnepk(lo[0],lo[1]); lf.y = rnepk(lo[2],lo[3]);
            lf.z = rnepk(lo[4],lo[5]); lf.w = rnepk(lo[6],lo[7]);
            u4* base = bigp + (size_t)((var*2+0)*16)*64;
            base[((c*2+0)*4 + Mi)*64 + lane] = hf;
            base[((c*2+1)*4 + Mi)*64 + lane] = lf;
        }
        {   // mat 1: wgcf = log2e*W2@Wg (fp32 dots from LDS, old prep0 order)
            unsigned hb[8]; float lo[8];
            #pragma unroll
            for (int jj = 0; jj < 8; ++jj) {
                const int r = k0 + ((jj < 4) ? jj : (12 + jj));   // j or 16+j
                float acc = 0.f;
                #pragma unroll 8
                for (int e = 0; e < 64; ++e) acc += sh[4096 + r*64 + e] * sh[e*64 + m];
                split1(LOG2E * acc, hb[jj], lo[jj]);
            }
            u4 hf, lf;
            hf.x = hb[0]|(hb[1]<<16); hf.y = hb[2]|(hb[3]<<16);
            hf.z = hb[4]|(hb[5]<<16); hf.w = hb[6]|(hb[7]<<16);
            lf.x = rnepk(lo[0],lo[1]); lf.y = rnepk(lo[2],lo[3]);
            lf.z = rnepk(lo[4],lo[5]); lf.w = rnepk(lo[6],lo[7]);
            u4* base = bigp + (size_t)((var*2+1)*16)*64;
            base[((c*2+0)*4 + Mi)*64 + lane] = hf;
            base[((c*2+1)*4 + Mi)*64 + lane] = lf;
        }
        if (c == 0 && tid < 64) {
            float acc = bg[var*64 + tid];
            #pragma unroll 8
            for (int e = 0; e < 64; ++e) acc += b2[var*64 + e] * sh[e*64 + tid];
            bgc[var*64 + tid] = LOG2E * acc;
        }
        return;
    }
    if (bid < 48) {
        // ---- type B: (var) — wtpp/wt1p packs + rpb ----
        const int var = bid - 32;
        const float* wpsrc = Wp + var*4096;
        const float* w1src = W1 + var*4096;
        const float* wtsrc = Wt + var*1024;
        #pragma unroll
        for (int i = 0; i < 16; ++i) sh[i*256 + tid]        = wpsrc[i*256 + tid];
        #pragma unroll
        for (int i = 0; i < 16; ++i) sh[4096 + i*256 + tid] = w1src[i*256 + tid];
        #pragma unroll
        for (int i = 0; i < 4; ++i)  sh[8192 + i*256 + tid] = wtsrc[i*256 + tid];
        __syncthreads();
        const int lane = tid & 63, Mi = tid >> 6;
        const int m = 16*Mi + (lane & 15), q = lane >> 4;
        float pv[4], p1[4];
        #pragma unroll
        for (int j = 0; j < 4; ++j) {
            const int v = 4*q + j;
            float ap = 0.f, a1 = 0.f;
            #pragma unroll 8
            for (int d = 0; d < 64; ++d) {
                const float w = sh[8192 + v*64 + d];
                ap += w * sh[d*64 + m];
                a1 += w * sh[4096 + d*64 + m];
            }
            pv[j] = ap; p1[j] = a1;
        }
        {
            f4 vv; vv.x = pv[0]; vv.y = pv[1]; vv.z = pv[2]; vv.w = pv[3];
            unsigned h0,h1,l0,l1; split4(vv,h0,h1,l0,l1);
            u4 o; o.x=h0; o.y=h1; o.z=l0; o.w=l1;
            wtpp[(var*4+Mi)*64 + lane] = o;
        }
        {
            f4 vv; vv.x = p1[0]; vv.y = p1[1]; vv.z = p1[2]; vv.w = p1[3];
            unsigned h0,h1,l0,l1; split4(vv,h0,h1,l0,l1);
            u4 o; o.x=h0; o.y=h1; o.z=l0; o.w=l1;
            wt1p[(var*4+Mi)*64 + lane] = o;
        }
        if (tid < 64) {
            float acc = bp[var*64 + tid];
            #pragma unroll 8
            for (int d = 0; d < 64; ++d) acc += bt[var*64 + d] * sh[d*64 + tid];
            rpb[var*64 + tid] = acc;
        }
        return;
    }
    if (bid < 304) {
        // ---- type C: cpb1[b][n][d] = (ctx@Wctx + bt)@W1 + b1  (fp32) ----
        const int sub = tid >> 6, d = tid & 63;
        const int bn = (bid - 48) * 4 + sub;
        const int b = bn >> 4, n = bn & 15;
        const float* __restrict__ wc = Wctx + n * DD * DD;
        const float* __restrict__ c  = ctx + b * DD;
        float acc = bt[n * DD + d];
        #pragma unroll 8
        for (int k = 0; k < DD; ++k) acc += c[k] * wc[k * DD + d];
        sh[sub*64 + d] = acc;                   // cprojb row
        __syncthreads();
        const float* __restrict__ w1 = W1 + n * DD * DD;
        float r = b1[n * DD + d];
        #pragma unroll 8
        for (int k = 0; k < DD; ++k) r += sh[sub*64 + k] * w1[k * DD + d];
        cpb1[bn * DD + d] = r;
        return;
    }
    {
        // ---- type D: Ws pack (full-K chunks c=0..7) ----
        const int r = (bid - 304) * 256 + tid;  // 0..511
        const int lane = r & 63, c = r >> 6;
        const int n = lane & 15, q = lane >> 4;
        const int k0 = 32*c + 4*q;
        unsigned hb[8]; float lo[8];
        #pragma unroll
        for (int j = 0; j < 4; ++j) split1(Ws[(k0+j)*16+n],    hb[j],   lo[j]);
        #pragma unroll
        for (int j = 0; j < 4; ++j) split1(Ws[(k0+16+j)*16+n], hb[4+j], lo[4+j]);
        u4 hf, lf;
        hf.x = hb[0]|(hb[1]<<16); hf.y = hb[2]|(hb[3]<<16);
        hf.z = hb[4]|(hb[5]<<16); hf.w = hb[6]|(hb[7]<<16);
        lf.x = rnepk(lo[0],lo[1]); lf.y = rnepk(lo[2],lo[3]);
        lf.z = rnepk(lo[4],lo[5]); lf.w = rnepk(lo[6],lo[7]);
        wsp[(c*2+0)*64 + lane] = hf;
        wsp[(c*2+1)*64 + lane] = lf;
    }
}

// Main: block = 512 threads = 8 waves, 64 tokens; grid = 512 (R0 skeleton).
// SESSION LEDGER (all measured):
//   R10 sumsq-LN        -> absmax 4x FAIL (cancellation; LN must be two-pass)
//   R11 pair-fusion@128  -> +16 held regs spill 453MB (R9 body fits EXACTLY)
//   R12 s_setprio(MFMA)  -> +17% (load-wave starvation + 53MB scratch)
//   R13 = R9 reproduced: vsn 91.0us  R14 8-deep batches: flat (compiler
//   already hoists) -> ALL vsn-side levers closed by measurement.
// R15: prep0+prep merged into ONE launch (folds computed in-block; bitwise
// identical packs) to attack the ~99us of non-vsn time (launch + serialization
// + fold round-trip). vsn untouched.
#define PSEL_OFF 0          // 128 rows x 68 dw = 8704 dw
#define WSEL_OFF 8704       // 4 tq x 16 n x 17 = 1088 dw
#define SMEM_DW  9792       // 39168 B; 2 blocks/CU = 78KB <= 160KB

__global__ __launch_bounds__(512, 4)
void vsn_kernel(const float* __restrict__ inp,
                const u4* __restrict__ wtpp, const u4* __restrict__ wt1p,
                const u4* __restrict__ bigp, const u4* __restrict__ wsp,
                const float* __restrict__ b2, const float* __restrict__ bgc,
                const float* __restrict__ rpb, const float* __restrict__ cpb1,
                const float* __restrict__ gamma_, const float* __restrict__ beta_,
                const float* __restrict__ bs,
                float* __restrict__ out_sel, float* __restrict__ out_w) {
    __shared__ float smem[SMEM_DW];

    const int tid  = threadIdx.x;
    const int lane = tid & 63;
    const int wv   = tid >> 6;
    const int grp  = wv & 1;                    // var group (8 vars)
    const int tq   = wv >> 1;                   // token quarter (16 tokens)
    const int qd   = lane >> 4;
    const int l15  = lane & 15;
    const int tile0 = blockIdx.x * 64;
    const int b     = blockIdx.x >> 3;          // tile0 / NT
    const int tok0  = tile0 + tq * 16;

    const float* row = inp + (size_t)(tok0 + l15) * FF;   // my token's feature row

    // ---------------- logits via MFMA + softmax (per wave, 16 tokens) -------
    {
        f4 lacc = *(const f4*)(bs + 4*qd);      // n = 4*qd + reg
        #pragma unroll 4
        for (int c = 0; c < 8; ++c) {
            const u4 wh = wsp[(c*2+0)*64 + lane];
            const u4 wl = wsp[(c*2+1)*64 + lane];
            const f4 v1 = *(const f4*)(row + 32*c + 4*qd);
            const f4 v2 = *(const f4*)(row + 32*c + 16 + 4*qd);
            unsigned h0,h1,l0,l1,h2,h3,l2,l3;
            split4f(v1,h0,h1,l0,l1);
            split4f(v2,h2,h3,l2,l3);
            const bf8 Bh = mk_b4(h0,h1,h2,h3);
            const bf8 Bl = mk_b4(l0,l1,l2,l3);
            lacc = __builtin_amdgcn_mfma_f32_16x16x32_bf16(afrag(wh), Bh, lacc, 0,0,0);
            lacc = __builtin_amdgcn_mfma_f32_16x16x32_bf16(afrag(wl), Bh, lacc, 0,0,0);
            lacc = __builtin_amdgcn_mfma_f32_16x16x32_bf16(afrag(wh), Bl, lacc, 0,0,0);
        }
        float mx = fmaxf(fmaxf(lacc.x,lacc.y), fmaxf(lacc.z,lacc.w));
        mx = fmaxf(mx, __shfl_xor(mx, 16));
        mx = fmaxf(mx, __shfl_xor(mx, 32));
        float e0 = __expf(lacc.x-mx), e1 = __expf(lacc.y-mx);
        float e2 = __expf(lacc.z-mx), e3 = __expf(lacc.w-mx);
        float s = e0+e1+e2+e3;
        s += __shfl_xor(s, 16);
        s += __shfl_xor(s, 32);
        const float rs = __builtin_amdgcn_rcpf(s);
        e0 *= rs; e1 *= rs; e2 *= rs; e3 *= rs;
        const int base = WSEL_OFF + tq*272 + (4*qd)*17 + l15;
        smem[base + 0*17] = e0;
        smem[base + 1*17] = e1;
        smem[base + 2*17] = e2;
        smem[base + 3*17] = e3;
        if (grp == 0) {
            f4 o; o.x=e0; o.y=e1; o.z=e2; o.w=e3;
            *(f4*)(out_w + (size_t)(tok0 + l15)*16 + 4*qd) = o;
        }
    }

    // ---------------- per-variable GRN chain (8 vars per wave) --------------
    const int sbase = PSEL_OFF + (grp*64 + tq*16 + l15)*68 + 4*qd;

    #pragma unroll 1
    for (int vi = 0; vi < 8; ++vi) {
        const int n = grp*8 + vi;
        unsigned fh[4][2], fl[4][2];

        // wall A (K=16 pair off xv): res = wtpf^T xv + rpb ; h1pre = wt1f^T xv + cpb1
        f4 racc[4], hacc[4];
        #pragma unroll
        for (int Mi = 0; Mi < 4; ++Mi) {
            racc[Mi] = *(const f4*)(rpb  + n*DD + 16*Mi + 4*qd);
            hacc[Mi] = *(const f4*)(cpb1 + (size_t)(b*NVAR+n)*DD + 16*Mi + 4*qd);
        }
        {
            const f4 v = *(const f4*)(row + n*16 + 4*qd);
            u4 wA[4], wB[4];
            #pragma unroll
            for (int Mi = 0; Mi < 4; ++Mi) {
                wA[Mi] = wtpp[(n*4+Mi)*64 + lane];
                wB[Mi] = wt1p[(n*4+Mi)*64 + lane];
            }
            unsigned xh0,xh1,xl0,xl1;
            split4f(v, xh0, xh1, xl0, xl1);
            const bf8 Bh = mk_bhh(xh0, xh1);
            const bf8 Bl = mk_bl0(xl0, xl1);
            #pragma unroll
            for (int Mi = 0; Mi < 4; ++Mi) {
                racc[Mi] = mfma2(racc[Mi], afrag(wA[Mi]), Bh, Bl);
                hacc[Mi] = mfma2(hacc[Mi], afrag(wB[Mi]), Bh, Bl);
            }
        }
        #pragma unroll
        for (int Mi = 0; Mi < 4; ++Mi) {
            f4& v = hacc[Mi];
            v.x = v.x > 0.f ? v.x : (__expf(v.x)-1.f);
            v.y = v.y > 0.f ? v.y : (__expf(v.y)-1.f);
            v.z = v.z > 0.f ? v.z : (__expf(v.z)-1.f);
            v.w = v.w > 0.f ? v.w : (__expf(v.w)-1.f);
        }
        acc_to_frags1(hacc, fh, fl);   // h1 frags

        // wall B: h2 = W2^T h1 + b2 ; g' = wgcf^T h1 + bgc  (shared h1-frags)
        f4 gacc[4];
        #pragma unroll
        for (int Mi = 0; Mi < 4; ++Mi) {
            hacc[Mi] = *(const f4*)(b2  + n*DD + 16*Mi + 4*qd);
            gacc[Mi] = *(const f4*)(bgc + n*DD + 16*Mi + 4*qd);
        }
        run_stage6_pair(bigp + (size_t)(n*2 + 0)*1024,
                        bigp + (size_t)(n*2 + 1)*1024, lane, fh, fl, hacc, gacc);

        // z = h2 * rcp(1 + exp2(-g')) + res
        f4 z[4];
        #pragma unroll
        for (int Mi = 0; Mi < 4; ++Mi) {
            const f4 gv = gacc[Mi];
            z[Mi].x = hacc[Mi].x * __builtin_amdgcn_rcpf(1.f + __builtin_amdgcn_exp2f(-gv.x)) + racc[Mi].x;
            z[Mi].y = hacc[Mi].y * __builtin_amdgcn_rcpf(1.f + __builtin_amdgcn_exp2f(-gv.y)) + racc[Mi].y;
            z[Mi].z = hacc[Mi].z * __builtin_amdgcn_rcpf(1.f + __builtin_amdgcn_exp2f(-gv.z)) + racc[Mi].z;
            z[Mi].w = hacc[Mi].w * __builtin_amdgcn_rcpf(1.f + __builtin_amdgcn_exp2f(-gv.w)) + racc[Mi].w;
        }
        // TWO-PASS LayerNorm (R10 lesson: sumsq form cancels — keep two-pass)
        float s = 0.f;
        #pragma unroll
        for (int Mi = 0; Mi < 4; ++Mi) s += z[Mi].x + z[Mi].y + z[Mi].z + z[Mi].w;
        s += __shfl_xor(s, 16);
        s += __shfl_xor(s, 32);
        const float mu = s * (1.f/64.f);
        float q = 0.f;
        #pragma unroll
        for (int Mi = 0; Mi < 4; ++Mi) {
            float dx = z[Mi].x - mu; q += dx*dx;
            dx = z[Mi].y - mu; q += dx*dx;
            dx = z[Mi].z - mu; q += dx*dx;
            dx = z[Mi].w - mu; q += dx*dx;
        }
        q += __shfl_xor(q, 16);
        q += __shfl_xor(q, 32);
        const float rstd = rsqrtf(q*(1.f/64.f) + LN_EPS);

        const float wn = smem[WSEL_OFF + tq*272 + n*17 + l15];
        #pragma unroll
        for (int Mi = 0; Mi < 4; ++Mi) {
            const f4 gm = *(const f4*)(gamma_ + n*DD + 16*Mi + 4*qd);
            const f4 bb = *(const f4*)(beta_  + n*DD + 16*Mi + 4*qd);
            f4 cb;
            cb.x = wn*((z[Mi].x-mu)*rstd*gm.x + bb.x);
            cb.y = wn*((z[Mi].y-mu)*rstd*gm.y + bb.y);
            cb.z = wn*((z[Mi].z-mu)*rstd*gm.z + bb.z);
            cb.w = wn*((z[Mi].w-mu)*rstd*gm.w + bb.w);
            if (vi == 0) {
                *(f4*)&smem[sbase + 16*Mi] = cb;
            } else {
                const f4 o = *(f4*)&smem[sbase + 16*Mi];
                *(f4*)&smem[sbase + 16*Mi] = o + cb;
            }
        }
    }

    __syncthreads();
    {
        const int tokloc = tid >> 3;            // 0..63
        const int d0 = (tid & 7) * 8;
        const int rbase = PSEL_OFF + tokloc*68 + d0;
        const f4 a0 = *(f4*)&smem[rbase];
        const f4 a1 = *(f4*)&smem[rbase + 4];
        const f4 b0 = *(f4*)&smem[rbase + 64*68];
        const f4 b1v = *(f4*)&smem[rbase + 64*68 + 4];
        float* po = out_sel + (size_t)(tile0+tokloc)*DD + d0;
        *(f4*)po     = a0 + b0;
        *(f4*)(po+4) = a1 + b1v;
    }
}

extern "C" void kernel_launch(void* const* d_in, const int* in_sizes, int n_in,
                              void* d_out, int out_size, void* d_ws, size_t ws_size,
                              hipStream_t stream) {
    const float* inp  = (const float*)d_in[0];
    const float* ctx  = (const float*)d_in[1];
    const float* Wt   = (const float*)d_in[2];
    const float* bt   = (const float*)d_in[3];
    const float* Wctx = (const float*)d_in[4];
    const float* W1   = (const float*)d_in[5];
    const float* b1   = (const float*)d_in[6];
    const float* W2   = (const float*)d_in[7];
    const float* b2   = (const float*)d_in[8];
    const float* Wg   = (const float*)d_in[9];
    const float* bg   = (const float*)d_in[10];
    const float* Wp   = (const float*)d_in[11];
    const float* bp   = (const float*)d_in[12];
    const float* gm   = (const float*)d_in[13];
    const float* bt2  = (const float*)d_in[14];
    const float* Ws   = (const float*)d_in[15];
    const float* bs   = (const float*)d_in[16];

    float* out_sel = (float*)d_out;
    float* out_w   = out_sel + (size_t)BT * DD;

    char* ws = (char*)d_ws;
    float* cpb1 = (float*)(ws + CPB1_OFF);
    float* rpb  = (float*)(ws + RPB_OFF);
    u4* wtpp = (u4*)(ws + WTPP_OFF);
    u4* wt1p = (u4*)(ws + WT1P_OFF);
    u4* bigp = (u4*)(ws + BIGP_OFF);
    u4* wsp  = (u4*)(ws + WSP_OFF);
    float* bgc  = (float*)(ws + BGC_OFF);

    prep_kernel<<<306, 256, 0, stream>>>(Wt, W1, W2, Wg, Wp, Ws, ctx, Wctx,
                                         bt, b1, b2, bg, bp,
                                         wtpp, wt1p, bigp, wsp, cpb1, rpb, bgc);
    vsn_kernel<<<BT / 64, 512, 0, stream>>>(inp, wtpp, wt1p, bigp, wsp,
                                            b2, bgc, rpb, cpb1, gm, bt2, bs,
                                            out_sel, out_w);
}

// Round 16
// 183.670 us; speedup vs baseline: 1.7805x; 1.0139x over previous
//
#include <hip/hip_runtime.h>

#define NB 64
#define NT 512
#define NVAR 16
#define VDIM 16
#define DD 64
#define FF 256
#define BT (NB*NT)
#define LN_EPS 1e-3f
#define LOG2E 1.4426950408889634f

typedef __attribute__((ext_vector_type(8))) short bf8;   // 8 bf16 = one MFMA A/B operand
typedef __attribute__((ext_vector_type(4))) float f4;
typedef __attribute__((ext_vector_type(4))) int i4;
typedef __attribute__((ext_vector_type(4))) unsigned u4;

// ---- ws layout (bytes) ----
// ALGEBRAIC FOLDS (all exact fp32, computed in-block at pack time — R15 merged
// the former prep0 into prep: folds never touch memory as f32):
//   rpb[n]     = bt@Wp + bp                      (res bias, per var)
//   cpb1[b][n] = (ctx@Wctx + bt)@W1 + b1         (h1 bias, per batch-var)
//   wtpp/wt1p  = packed Wt@Wp, Wt@W1             (K=16 mats off xv)
//   bigp mat1  = packed log2e*W2@Wg; bgc = log2e*(b2@Wg+bg)  (gate through W2)
// vsn walls per var: A) K=16 pair off xv  B) K=64 pair off h1.
#define CPB1_OFF   0                  // 64*16*64 f32 = 256KB
#define RPB_OFF    262144             // 16*64 f32 = 4KB
#define WTPP_OFF   266240             // packed Wt@Wp: 16v x 4Mi x 64 x 16B = 64KB
#define WT1P_OFF   331776             // packed Wt@W1: 64KB
#define BIGP_OFF   397312             // 2 mats x 16v x 16 frags x 64 x 16B = 512KB
#define WSP_OFF    921600             // 16 frags x 64 x 16B = 16KB
#define BGC_OFF    937984             // 16*64 f32 = 4KB
// bigp frag layout per var-mat (16 frags): idx = (c*2+hl)*4 + Mi ; mats 0=W2 1=wgcf

// ---- precise RNE split (prep-time only) ----
__device__ __forceinline__ void split1(float x, unsigned &hb, float &lo) {
    unsigned u = __builtin_bit_cast(unsigned, x);
    unsigned r = u + 0x7fffu + ((u >> 16) & 1u);
    hb = r >> 16;
    lo = x - __builtin_bit_cast(float, r & 0xffff0000u);
}
__device__ __forceinline__ unsigned rnepk(float x, float y) {
    unsigned a = __builtin_bit_cast(unsigned, x);
    unsigned b = __builtin_bit_cast(unsigned, y);
    a = a + 0x7fffu + ((a >> 16) & 1u);
    b = b + 0x7fffu + ((b >> 16) & 1u);
    return (a >> 16) | (b & 0xffff0000u);
}
__device__ __forceinline__ void split4(f4 v, unsigned &h0, unsigned &h1,
                                       unsigned &l0, unsigned &l1) {
    unsigned b0,b1,b2,b3; float q0,q1,q2,q3;
    split1(v.x,b0,q0); split1(v.y,b1,q1); split1(v.z,b2,q2); split1(v.w,b3,q3);
    h0 = b0 | (b1<<16); h1 = b2 | (b3<<16);
    l0 = rnepk(q0,q1); l1 = rnepk(q2,q3);
}
// ---- fast truncation split (hot path): hi = trunc(x), lo = trunc(x - hi) ----
__device__ __forceinline__ void split4f(f4 v, unsigned &h0, unsigned &h1,
                                        unsigned &l0, unsigned &l1) {
    unsigned a0 = __builtin_bit_cast(unsigned, v.x);
    unsigned a1 = __builtin_bit_cast(unsigned, v.y);
    unsigned a2 = __builtin_bit_cast(unsigned, v.z);
    unsigned a3 = __builtin_bit_cast(unsigned, v.w);
    unsigned m0 = a0 & 0xffff0000u, m1 = a1 & 0xffff0000u;
    unsigned m2 = a2 & 0xffff0000u, m3 = a3 & 0xffff0000u;
    h0 = (a0 >> 16) | m1;
    h1 = (a2 >> 16) | m3;
    float lx = v.x - __builtin_bit_cast(float, m0);
    float ly = v.y - __builtin_bit_cast(float, m1);
    float lz = v.z - __builtin_bit_cast(float, m2);
    float lw = v.w - __builtin_bit_cast(float, m3);
    l0 = (__builtin_bit_cast(unsigned, lx) >> 16) |
         (__builtin_bit_cast(unsigned, ly) & 0xffff0000u);
    l1 = (__builtin_bit_cast(unsigned, lz) >> 16) |
         (__builtin_bit_cast(unsigned, lw) & 0xffff0000u);
}
__device__ __forceinline__ bf8 afrag(u4 w) { return __builtin_bit_cast(bf8, w); }
__device__ __forceinline__ bf8 mk_b4(unsigned w0, unsigned w1, unsigned w2, unsigned w3) {
    i4 t; t.x = (int)w0; t.y = (int)w1; t.z = (int)w2; t.w = (int)w3;
    return __builtin_bit_cast(bf8, t);
}
// duplicated-B operands (K=16 stages)
__device__ __forceinline__ bf8 mk_bhh(unsigned h0, unsigned h1) {
    i4 t; t.x = (int)h0; t.y = (int)h1; t.z = (int)h0; t.w = (int)h1;
    return __builtin_bit_cast(bf8, t);
}
__device__ __forceinline__ bf8 mk_bl0(unsigned l0, unsigned l1) {
    i4 t; t.x = (int)l0; t.y = (int)l1; t.z = 0; t.w = 0;
    return __builtin_bit_cast(bf8, t);
}

__device__ __forceinline__ f4 mfma2(f4 acc, bf8 Af, bf8 Bh, bf8 Bl) {
    acc = __builtin_amdgcn_mfma_f32_16x16x32_bf16(Af, Bh, acc, 0,0,0);
    acc = __builtin_amdgcn_mfma_f32_16x16x32_bf16(Af, Bl, acc, 0,0,0);
    return acc;
}

// acc (C-layout) -> B-operand frags of the next stage (pure in-lane repack)
__device__ __forceinline__ void acc_to_frags1(const f4 acc[4],
        unsigned fh[4][2], unsigned fl[4][2]) {
    #pragma unroll
    for (int Ks = 0; Ks < 4; ++Ks)
        split4f(acc[Ks], fh[Ks][0], fh[Ks][1], fl[Ks][0], fl[Ks][1]);
}
// Paired 64x64 GEMM-stage, full-K: both mats consume the SAME B operands.
// 6 MFMAs per Mi per mat; terms Wh.xh + Wl.xh + Wh.xl (Wl.xl ~2^-16 dropped).
// R16 CROSS-WALL PREFETCH: the Mi=0 batches of both mats (p0*, p1*) are loaded
// by the CALLER before the ELU/frag block (no dependency on wall A results) —
// the compiler won't hoist across that region on its own (loads stay near
// uses under pressure; R14 showed only within-region hoisting). Mi=1..3 load
// inline as before. Identical MFMA order -> identical numerics.
// NOTE (R12): do NOT wrap in s_setprio — measured +17% regression.
__device__ __forceinline__ void run_stage6_pair_pre(const u4* __restrict__ ap0,
        const u4* __restrict__ ap1, int lane,
        const unsigned fh[4][2], const unsigned fl[4][2], f4 acc0[4], f4 acc1[4],
        u4 p00, u4 p01, u4 p02, u4 p03, u4 p10, u4 p11, u4 p12, u4 p13) {
    const bf8 Bh0 = mk_b4(fh[0][0], fh[0][1], fh[1][0], fh[1][1]);
    const bf8 Bh1 = mk_b4(fh[2][0], fh[2][1], fh[3][0], fh[3][1]);
    const bf8 Bl0 = mk_b4(fl[0][0], fl[0][1], fl[1][0], fl[1][1]);
    const bf8 Bl1 = mk_b4(fl[2][0], fl[2][1], fl[3][0], fl[3][1]);
    {   // Mi = 0: consume preloaded batches
        f4 a = acc0[0];
        a = __builtin_amdgcn_mfma_f32_16x16x32_bf16(afrag(p00), Bh0, a, 0,0,0);
        a = __builtin_amdgcn_mfma_f32_16x16x32_bf16(afrag(p02), Bh1, a, 0,0,0);
        a = __builtin_amdgcn_mfma_f32_16x16x32_bf16(afrag(p01), Bh0, a, 0,0,0);
        a = __builtin_amdgcn_mfma_f32_16x16x32_bf16(afrag(p03), Bh1, a, 0,0,0);
        a = __builtin_amdgcn_mfma_f32_16x16x32_bf16(afrag(p00), Bl0, a, 0,0,0);
        a = __builtin_amdgcn_mfma_f32_16x16x32_bf16(afrag(p02), Bl1, a, 0,0,0);
        acc0[0] = a;
        f4 g = acc1[0];
        g = __builtin_amdgcn_mfma_f32_16x16x32_bf16(afrag(p10), Bh0, g, 0,0,0);
        g = __builtin_amdgcn_mfma_f32_16x16x32_bf16(afrag(p12), Bh1, g, 0,0,0);
        g = __builtin_amdgcn_mfma_f32_16x16x32_bf16(afrag(p11), Bh0, g, 0,0,0);
        g = __builtin_amdgcn_mfma_f32_16x16x32_bf16(afrag(p13), Bh1, g, 0,0,0);
        g = __builtin_amdgcn_mfma_f32_16x16x32_bf16(afrag(p10), Bl0, g, 0,0,0);
        g = __builtin_amdgcn_mfma_f32_16x16x32_bf16(afrag(p12), Bl1, g, 0,0,0);
        acc1[0] = g;
    }
    #pragma unroll
    for (int Mi = 1; Mi < 4; ++Mi) {
        const u4 a00 = ap0[(     Mi)*64 + lane];
        const u4 a01 = ap0[( 4 + Mi)*64 + lane];
        const u4 a02 = ap0[( 8 + Mi)*64 + lane];
        const u4 a03 = ap0[(12 + Mi)*64 + lane];
        const u4 a10 = ap1[(     Mi)*64 + lane];
        const u4 a11 = ap1[( 4 + Mi)*64 + lane];
        const u4 a12 = ap1[( 8 + Mi)*64 + lane];
        const u4 a13 = ap1[(12 + Mi)*64 + lane];
        f4 a = acc0[Mi];
        a = __builtin_amdgcn_mfma_f32_16x16x32_bf16(afrag(a00), Bh0, a, 0,0,0);
        a = __builtin_amdgcn_mfma_f32_16x16x32_bf16(afrag(a02), Bh1, a, 0,0,0);
        a = __builtin_amdgcn_mfma_f32_16x16x32_bf16(afrag(a01), Bh0, a, 0,0,0);
        a = __builtin_amdgcn_mfma_f32_16x16x32_bf16(afrag(a03), Bh1, a, 0,0,0);
        a = __builtin_amdgcn_mfma_f32_16x16x32_bf16(afrag(a00), Bl0, a, 0,0,0);
        a = __builtin_amdgcn_mfma_f32_16x16x32_bf16(afrag(a02), Bl1, a, 0,0,0);
        acc0[Mi] = a;
        f4 g = acc1[Mi];
        g = __builtin_amdgcn_mfma_f32_16x16x32_bf16(afrag(a10), Bh0, g, 0,0,0);
        g = __builtin_amdgcn_mfma_f32_16x16x32_bf16(afrag(a12), Bh1, g, 0,0,0);
        g = __builtin_amdgcn_mfma_f32_16x16x32_bf16(afrag(a11), Bh0, g, 0,0,0);
        g = __builtin_amdgcn_mfma_f32_16x16x32_bf16(afrag(a13), Bh1, g, 0,0,0);
        g = __builtin_amdgcn_mfma_f32_16x16x32_bf16(afrag(a10), Bl0, g, 0,0,0);
        g = __builtin_amdgcn_mfma_f32_16x16x32_bf16(afrag(a12), Bl1, g, 0,0,0);
        acc1[Mi] = g;
    }
}

// MERGED prep (R15): one launch, 306 blocks. Folds computed in-block from
// LDS-staged operands — identical fp32 dot order as the old prep0.
//   blocks 0..31   (var,c): W2 frags (mat0) + wgcf frags (mat1); bgc on c==0.
//   blocks 32..47  (var): wtpp/wt1p packs + rpb.
//   blocks 48..303 cpb1[b][n] (4 rows/block)
//   blocks 304..305 wsp pack
__global__ void prep_kernel(const float* __restrict__ Wt, const float* __restrict__ W1,
                            const float* __restrict__ W2, const float* __restrict__ Wg,
                            const float* __restrict__ Wp, const float* __restrict__ Ws,
                            const float* __restrict__ ctx, const float* __restrict__ Wctx,
                            const float* __restrict__ bt, const float* __restrict__ b1,
                            const float* __restrict__ b2, const float* __restrict__ bg,
                            const float* __restrict__ bp,
                            u4* __restrict__ wtpp, u4* __restrict__ wt1p,
                            u4* __restrict__ bigp, u4* __restrict__ wsp,
                            float* __restrict__ cpb1, float* __restrict__ rpb,
                            float* __restrict__ bgc) {
    __shared__ float sh[9216];
    const int tid = threadIdx.x;
    const int bid = blockIdx.x;
    if (bid < 32) {
        // ---- type A: (var, c) — W2 frags + wgcf frags + bgc ----
        const int var = bid >> 1, c = bid & 1;
        const float* wgsrc = Wg + var*4096;
        const float* w2src = W2 + var*4096 + c*32*64;    // rows [32c, 32c+32)
        #pragma unroll
        for (int i = 0; i < 16; ++i) sh[i*256 + tid] = wgsrc[i*256 + tid];
        #pragma unroll
        for (int i = 0; i < 8; ++i)  sh[4096 + i*256 + tid] = w2src[i*256 + tid];
        __syncthreads();
        const int lane = tid & 63, Mi = tid >> 6;
        const int m = 16*Mi + (lane & 15), q = lane >> 4;
        const int k0 = 4*q;                               // local row in window
        {   // mat 0: W2 frags (straight split of staged rows)
            unsigned hb[8]; float lo[8];
            #pragma unroll
            for (int j = 0; j < 4; ++j) split1(sh[4096 + (k0+j)*64 + m],    hb[j],   lo[j]);
            #pragma unroll
            for (int j = 0; j < 4; ++j) split1(sh[4096 + (k0+16+j)*64 + m], hb[4+j], lo[4+j]);
            u4 hf, lf;
            hf.x = hb[0]|(hb[1]<<16); hf.y = hb[2]|(hb[3]<<16);
            hf.z = hb[4]|(hb[5]<<16); hf.w = hb[6]|(hb[7]<<16);
            lf.x = rnepk(lo[0],lo[1]); lf.y = rnepk(lo[2],lo[3]);
            lf.z = rnepk(lo[4],lo[5]); lf.w = rnepk(lo[6],lo[7]);
            u4* base = bigp + (size_t)((var*2+0)*16)*64;
            base[((c*2+0)*4 + Mi)*64 + lane] = hf;
            base[((c*2+1)*4 + Mi)*64 + lane] = lf;
        }
        {   // mat 1: wgcf = log2e*W2@Wg (fp32 dots from LDS, old prep0 order)
            unsigned hb[8]; float lo[8];
            #pragma unroll
            for (int jj = 0; jj < 8; ++jj) {
                const int r = k0 + ((jj < 4) ? jj : (12 + jj));   // j or 16+j
                float acc = 0.f;
                #pragma unroll 8
                for (int e = 0; e < 64; ++e) acc += sh[4096 + r*64 + e] * sh[e*64 + m];
                split1(LOG2E * acc, hb[jj], lo[jj]);
            }
            u4 hf, lf;
            hf.x = hb[0]|(hb[1]<<16); hf.y = hb[2]|(hb[3]<<16);
            hf.z = hb[4]|(hb[5]<<16); hf.w = hb[6]|(hb[7]<<16);
            lf.x = rnepk(lo[0],lo[1]); lf.y = rnepk(lo[2],lo[3]);
            lf.z = rnepk(lo[4],lo[5]); lf.w = rnepk(lo[6],lo[7]);
            u4* base = bigp + (size_t)((var*2+1)*16)*64;
            base[((c*2+0)*4 + Mi)*64 + lane] = hf;
            base[((c*2+1)*4 + Mi)*64 + lane] = lf;
        }
        if (c == 0 && tid < 64) {
            float acc = bg[var*64 + tid];
            #pragma unroll 8
            for (int e = 0; e < 64; ++e) acc += b2[var*64 + e] * sh[e*64 + tid];
            bgc[var*64 + tid] = LOG2E * acc;
        }
        return;
    }
    if (bid < 48) {
        // ---- type B: (var) — wtpp/wt1p packs + rpb ----
        const int var = bid - 32;
        const float* wpsrc = Wp + var*4096;
        const float* w1src = W1 + var*4096;
        const float* wtsrc = Wt + var*1024;
        #pragma unroll
        for (int i = 0; i < 16; ++i) sh[i*256 + tid]        = wpsrc[i*256 + tid];
        #pragma unroll
        for (int i = 0; i < 16; ++i) sh[4096 + i*256 + tid] = w1src[i*256 + tid];
        #pragma unroll
        for (int i = 0; i < 4; ++i)  sh[8192 + i*256 + tid] = wtsrc[i*256 + tid];
        __syncthreads();
        const int lane = tid & 63, Mi = tid >> 6;
        const int m = 16*Mi + (lane & 15), q = lane >> 4;
        float pv[4], p1[4];
        #pragma unroll
        for (int j = 0; j < 4; ++j) {
            const int v = 4*q + j;
            float ap = 0.f, a1 = 0.f;
            #pragma unroll 8
            for (int d = 0; d < 64; ++d) {
                const float w = sh[8192 + v*64 + d];
                ap += w * sh[d*64 + m];
                a1 += w * sh[4096 + d*64 + m];
            }
            pv[j] = ap; p1[j] = a1;
        }
        {
            f4 vv; vv.x = pv[0]; vv.y = pv[1]; vv.z = pv[2]; vv.w = pv[3];
            unsigned h0,h1,l0,l1; split4(vv,h0,h1,l0,l1);
            u4 o; o.x=h0; o.y=h1; o.z=l0; o.w=l1;
            wtpp[(var*4+Mi)*64 + lane] = o;
        }
        {
            f4 vv; vv.x = p1[0]; vv.y = p1[1]; vv.z = p1[2]; vv.w = p1[3];
            unsigned h0,h1,l0,l1; split4(vv,h0,h1,l0,l1);
            u4 o; o.x=h0; o.y=h1; o.z=l0; o.w=l1;
            wt1p[(var*4+Mi)*64 + lane] = o;
        }
        if (tid < 64) {
            float acc = bp[var*64 + tid];
            #pragma unroll 8
            for (int d = 0; d < 64; ++d) acc += bt[var*64 + d] * sh[d*64 + tid];
            rpb[var*64 + tid] = acc;
        }
        return;
    }
    if (bid < 304) {
        // ---- type C: cpb1[b][n][d] = (ctx@Wctx + bt)@W1 + b1  (fp32) ----
        const int sub = tid >> 6, d = tid & 63;
        const int bn = (bid - 48) * 4 + sub;
        const int b = bn >> 4, n = bn & 15;
        const float* __restrict__ wc = Wctx + n * DD * DD;
        const float* __restrict__ c  = ctx + b * DD;
        float acc = bt[n * DD + d];
        #pragma unroll 8
        for (int k = 0; k < DD; ++k) acc += c[k] * wc[k * DD + d];
        sh[sub*64 + d] = acc;                   // cprojb row
        __syncthreads();
        const float* __restrict__ w1 = W1 + n * DD * DD;
        float r = b1[n * DD + d];
        #pragma unroll 8
        for (int k = 0; k < DD; ++k) r += sh[sub*64 + k] * w1[k * DD + d];
        cpb1[bn * DD + d] = r;
        return;
    }
    {
        // ---- type D: Ws pack (full-K chunks c=0..7) ----
        const int r = (bid - 304) * 256 + tid;  // 0..511
        const int lane = r & 63, c = r >> 6;
        const int n = lane & 15, q = lane >> 4;
        const int k0 = 32*c + 4*q;
        unsigned hb[8]; float lo[8];
        #pragma unroll
        for (int j = 0; j < 4; ++j) split1(Ws[(k0+j)*16+n],    hb[j],   lo[j]);
        #pragma unroll
        for (int j = 0; j < 4; ++j) split1(Ws[(k0+16+j)*16+n], hb[4+j], lo[4+j]);
        u4 hf, lf;
        hf.x = hb[0]|(hb[1]<<16); hf.y = hb[2]|(hb[3]<<16);
        hf.z = hb[4]|(hb[5]<<16); hf.w = hb[6]|(hb[7]<<16);
        lf.x = rnepk(lo[0],lo[1]); lf.y = rnepk(lo[2],lo[3]);
        lf.z = rnepk(lo[4],lo[5]); lf.w = rnepk(lo[6],lo[7]);
        wsp[(c*2+0)*64 + lane] = hf;
        wsp[(c*2+1)*64 + lane] = lf;
    }
}

// Main: block = 512 threads = 8 waves, 64 tokens; grid = 512 (R0 skeleton).
// SESSION LEDGER (all measured):
//   R10 sumsq-LN        -> absmax 4x FAIL (LN must stay two-pass)
//   R11 pair-fusion@128  -> +16 held regs spill 453MB (R9 body fits EXACTLY)
//   R12 s_setprio(MFMA)  -> +17% (load-wave starvation + scratch)
//   R13=R9 optimum reproduced (vsn 91.0)  R14 in-wall load batching: flat
//   R15 prep merge: total 189.8 -> 186.2 (launch + fold round-trip removed)
// R16 (this): cross-wall prefetch — wall B's Mi=0 batches issued BEFORE the
// ELU/frag block (no deps; compiler won't hoist across it). 32 transient
// regs, short hold — the category R14 proved safe.
#define PSEL_OFF 0          // 128 rows x 68 dw = 8704 dw
#define WSEL_OFF 8704       // 4 tq x 16 n x 17 = 1088 dw
#define SMEM_DW  9792       // 39168 B; 2 blocks/CU = 78KB <= 160KB

__global__ __launch_bounds__(512, 4)
void vsn_kernel(const float* __restrict__ inp,
                const u4* __restrict__ wtpp, const u4* __restrict__ wt1p,
                const u4* __restrict__ bigp, const u4* __restrict__ wsp,
                const float* __restrict__ b2, const float* __restrict__ bgc,
                const float* __restrict__ rpb, const float* __restrict__ cpb1,
                const float* __restrict__ gamma_, const float* __restrict__ beta_,
                const float* __restrict__ bs,
                float* __restrict__ out_sel, float* __restrict__ out_w) {
    __shared__ float smem[SMEM_DW];

    const int tid  = threadIdx.x;
    const int lane = tid & 63;
    const int wv   = tid >> 6;
    const int grp  = wv & 1;                    // var group (8 vars)
    const int tq   = wv >> 1;                   // token quarter (16 tokens)
    const int qd   = lane >> 4;
    const int l15  = lane & 15;
    const int tile0 = blockIdx.x * 64;
    const int b     = blockIdx.x >> 3;          // tile0 / NT
    const int tok0  = tile0 + tq * 16;

    const float* row = inp + (size_t)(tok0 + l15) * FF;   // my token's feature row

    // ---------------- logits via MFMA + softmax (per wave, 16 tokens) -------
    {
        f4 lacc = *(const f4*)(bs + 4*qd);      // n = 4*qd + reg
        #pragma unroll 4
        for (int c = 0; c < 8; ++c) {
            const u4 wh = wsp[(c*2+0)*64 + lane];
            const u4 wl = wsp[(c*2+1)*64 + lane];
            const f4 v1 = *(const f4*)(row + 32*c + 4*qd);
            const f4 v2 = *(const f4*)(row + 32*c + 16 + 4*qd);
            unsigned h0,h1,l0,l1,h2,h3,l2,l3;
            split4f(v1,h0,h1,l0,l1);
            split4f(v2,h2,h3,l2,l3);
            const bf8 Bh = mk_b4(h0,h1,h2,h3);
            const bf8 Bl = mk_b4(l0,l1,l2,l3);
            lacc = __builtin_amdgcn_mfma_f32_16x16x32_bf16(afrag(wh), Bh, lacc, 0,0,0);
            lacc = __builtin_amdgcn_mfma_f32_16x16x32_bf16(afrag(wl), Bh, lacc, 0,0,0);
            lacc = __builtin_amdgcn_mfma_f32_16x16x32_bf16(afrag(wh), Bl, lacc, 0,0,0);
        }
        float mx = fmaxf(fmaxf(lacc.x,lacc.y), fmaxf(lacc.z,lacc.w));
        mx = fmaxf(mx, __shfl_xor(mx, 16));
        mx = fmaxf(mx, __shfl_xor(mx, 32));
        float e0 = __expf(lacc.x-mx), e1 = __expf(lacc.y-mx);
        float e2 = __expf(lacc.z-mx), e3 = __expf(lacc.w-mx);
        float s = e0+e1+e2+e3;
        s += __shfl_xor(s, 16);
        s += __shfl_xor(s, 32);
        const float rs = __builtin_amdgcn_rcpf(s);
        e0 *= rs; e1 *= rs; e2 *= rs; e3 *= rs;
        const int base = WSEL_OFF + tq*272 + (4*qd)*17 + l15;
        smem[base + 0*17] = e0;
        smem[base + 1*17] = e1;
        smem[base + 2*17] = e2;
        smem[base + 3*17] = e3;
        if (grp == 0) {
            f4 o; o.x=e0; o.y=e1; o.z=e2; o.w=e3;
            *(f4*)(out_w + (size_t)(tok0 + l15)*16 + 4*qd) = o;
        }
    }

    // ---------------- per-variable GRN chain (8 vars per wave) --------------
    const int sbase = PSEL_OFF + (grp*64 + tq*16 + l15)*68 + 4*qd;

    #pragma unroll 1
    for (int vi = 0; vi < 8; ++vi) {
        const int n = grp*8 + vi;
        unsigned fh[4][2], fl[4][2];

        // wall A (K=16 pair off xv): res = wtpf^T xv + rpb ; h1pre = wt1f^T xv + cpb1
        f4 racc[4], hacc[4];
        #pragma unroll
        for (int Mi = 0; Mi < 4; ++Mi) {
            racc[Mi] = *(const f4*)(rpb  + n*DD + 16*Mi + 4*qd);
            hacc[Mi] = *(const f4*)(cpb1 + (size_t)(b*NVAR+n)*DD + 16*Mi + 4*qd);
        }
        {
            const f4 v = *(const f4*)(row + n*16 + 4*qd);
            u4 wA[4], wB[4];
            #pragma unroll
            for (int Mi = 0; Mi < 4; ++Mi) {
                wA[Mi] = wtpp[(n*4+Mi)*64 + lane];
                wB[Mi] = wt1p[(n*4+Mi)*64 + lane];
            }
            unsigned xh0,xh1,xl0,xl1;
            split4f(v, xh0, xh1, xl0, xl1);
            const bf8 Bh = mk_bhh(xh0, xh1);
            const bf8 Bl = mk_bl0(xl0, xl1);
            #pragma unroll
            for (int Mi = 0; Mi < 4; ++Mi) {
                racc[Mi] = mfma2(racc[Mi], afrag(wA[Mi]), Bh, Bl);
                hacc[Mi] = mfma2(hacc[Mi], afrag(wB[Mi]), Bh, Bl);
            }
        }
        // ---- cross-wall prefetch: wall B Mi=0 batches (no deps on wall A) ---
        const u4* bp0 = bigp + (size_t)(n*2 + 0)*1024;
        const u4* bp1 = bigp + (size_t)(n*2 + 1)*1024;
        const u4 p00 = bp0[ 0*64 + lane];
        const u4 p01 = bp0[ 4*64 + lane];
        const u4 p02 = bp0[ 8*64 + lane];
        const u4 p03 = bp0[12*64 + lane];
        const u4 p10 = bp1[ 0*64 + lane];
        const u4 p11 = bp1[ 4*64 + lane];
        const u4 p12 = bp1[ 8*64 + lane];
        const u4 p13 = bp1[12*64 + lane];

        #pragma unroll
        for (int Mi = 0; Mi < 4; ++Mi) {
            f4& v = hacc[Mi];
            v.x = v.x > 0.f ? v.x : (__expf(v.x)-1.f);
            v.y = v.y > 0.f ? v.y : (__expf(v.y)-1.f);
            v.z = v.z > 0.f ? v.z : (__expf(v.z)-1.f);
            v.w = v.w > 0.f ? v.w : (__expf(v.w)-1.f);
        }
        acc_to_frags1(hacc, fh, fl);   // h1 frags

        // wall B: h2 = W2^T h1 + b2 ; g' = wgcf^T h1 + bgc  (shared h1-frags)
        f4 gacc[4];
        #pragma unroll
        for (int Mi = 0; Mi < 4; ++Mi) {
            hacc[Mi] = *(const f4*)(b2  + n*DD + 16*Mi + 4*qd);
            gacc[Mi] = *(const f4*)(bgc + n*DD + 16*Mi + 4*qd);
        }
        run_stage6_pair_pre(bp0, bp1, lane, fh, fl, hacc, gacc,
                            p00, p01, p02, p03, p10, p11, p12, p13);

        // z = h2 * rcp(1 + exp2(-g')) + res
        f4 z[4];
        #pragma unroll
        for (int Mi = 0; Mi < 4; ++Mi) {
            const f4 gv = gacc[Mi];
            z[Mi].x = hacc[Mi].x * __builtin_amdgcn_rcpf(1.f + __builtin_amdgcn_exp2f(-gv.x)) + racc[Mi].x;
            z[Mi].y = hacc[Mi].y * __builtin_amdgcn_rcpf(1.f + __builtin_amdgcn_exp2f(-gv.y)) + racc[Mi].y;
            z[Mi].z = hacc[Mi].z * __builtin_amdgcn_rcpf(1.f + __builtin_amdgcn_exp2f(-gv.z)) + racc[Mi].z;
            z[Mi].w = hacc[Mi].w * __builtin_amdgcn_rcpf(1.f + __builtin_amdgcn_exp2f(-gv.w)) + racc[Mi].w;
        }
        // TWO-PASS LayerNorm (R10 lesson: sumsq form cancels — keep two-pass)
        float s = 0.f;
        #pragma unroll
        for (int Mi = 0; Mi < 4; ++Mi) s += z[Mi].x + z[Mi].y + z[Mi].z + z[Mi].w;
        s += __shfl_xor(s, 16);
        s += __shfl_xor(s, 32);
        const float mu = s * (1.f/64.f);
        float q = 0.f;
        #pragma unroll
        for (int Mi = 0; Mi < 4; ++Mi) {
            float dx = z[Mi].x - mu; q += dx*dx;
            dx = z[Mi].y - mu; q += dx*dx;
            dx = z[Mi].z - mu; q += dx*dx;
            dx = z[Mi].w - mu; q += dx*dx;
        }
        q += __shfl_xor(q, 16);
        q += __shfl_xor(q, 32);
        const float rstd = rsqrtf(q*(1.f/64.f) + LN_EPS);

        const float wn = smem[WSEL_OFF + tq*272 + n*17 + l15];
        #pragma unroll
        for (int Mi = 0; Mi < 4; ++Mi) {
            const f4 gm = *(const f4*)(gamma_ + n*DD + 16*Mi + 4*qd);
            const f4 bb = *(const f4*)(beta_  + n*DD + 16*Mi + 4*qd);
            f4 cb;
            cb.x = wn*((z[Mi].x-mu)*rstd*gm.x + bb.x);
            cb.y = wn*((z[Mi].y-mu)*rstd*gm.y + bb.y);
            cb.z = wn*((z[Mi].z-mu)*rstd*gm.z + bb.z);
            cb.w = wn*((z[Mi].w-mu)*rstd*gm.w + bb.w);
            if (vi == 0) {
                *(f4*)&smem[sbase + 16*Mi] = cb;
            } else {
                const f4 o = *(f4*)&smem[sbase + 16*Mi];
                *(f4*)&smem[sbase + 16*Mi] = o + cb;
            }
        }
    }

    __syncthreads();
    {
        const int tokloc = tid >> 3;            // 0..63
        const int d0 = (tid & 7) * 8;
        const int rbase = PSEL_OFF + tokloc*68 + d0;
        const f4 a0 = *(f4*)&smem[rbase];
        const f4 a1 = *(f4*)&smem[rbase + 4];
        const f4 b0 = *(f4*)&smem[rbase + 64*68];
        const f4 b1v = *(f4*)&smem[rbase + 64*68 + 4];
        float* po = out_sel + (size_t)(tile0+tokloc)*DD + d0;
        *(f4*)po     = a0 + b0;
        *(f4*)(po+4) = a1 + b1v;
    }
}

extern "C" void kernel_launch(void* const* d_in, const int* in_sizes, int n_in,
                              void* d_out, int out_size, void* d_ws, size_t ws_size,
                              hipStream_t stream) {
    const float* inp  = (const float*)d_in[0];
    const float* ctx  = (const float*)d_in[1];
    const float* Wt   = (const float*)d_in[2];
    const float* bt   = (const float*)d_in[3];
    const float* Wctx = (const float*)d_in[4];
    const float* W1   = (const float*)d_in[5];
    const float* b1   = (const float*)d_in[6];
    const float* W2   = (const float*)d_in[7];
    const float* b2   = (const float*)d_in[8];
    const float* Wg   = (const float*)d_in[9];
    const float* bg   = (const float*)d_in[10];
    const float* Wp   = (const float*)d_in[11];
    const float* bp   = (const float*)d_in[12];
    const float* gm   = (const float*)d_in[13];
    const float* bt2  = (const float*)d_in[14];
    const float* Ws   = (const float*)d_in[15];
    const float* bs   = (const float*)d_in[16];

    float* out_sel = (float*)d_out;
    float* out_w   = out_sel + (size_t)BT * DD;

    char* ws = (char*)d_ws;
    float* cpb1 = (float*)(ws + CPB1_OFF);
    float* rpb  = (float*)(ws + RPB_OFF);
    u4* wtpp = (u4*)(ws + WTPP_OFF);
    u4* wt1p = (u4*)(ws + WT1P_OFF);
    u4* bigp = (u4*)(ws + BIGP_OFF);
    u4* wsp  = (u4*)(ws + WSP_OFF);
    float* bgc  = (float*)(ws + BGC_OFF);

    prep_kernel<<<306, 256, 0, stream>>>(Wt, W1, W2, Wg, Wp, Ws, ctx, Wctx,
                                         bt, b1, b2, bg, bp,
                                         wtpp, wt1p, bigp, wsp, cpb1, rpb, bgc);
    vsn_kernel<<<BT / 64, 512, 0, stream>>>(inp, wtpp, wt1p, bigp, wsp,
                                            b2, bgc, rpb, cpb1, gm, bt2, bs,
                                            out_sel, out_w);
}